// Round 12
// baseline (179.406 us; speedup 1.0000x reference)
//
#include <hip/hip_runtime.h>
#include <hip/hip_bf16.h>
#include <cstdint>

// Sizes
#define Bz 4
#define Tz 256
#define Dz 256
#define D2z 512
#define Hz 4
#define DHz 128
#define BT (Bz*Tz)          // 1024 rows
#define XLS 133120          // padded xl: per-batch stride = (4+256)*512
#define XLP 4               // 4 zero pad rows per batch (causal t<0)

__device__ __forceinline__ float dot4(float4 a, float4 b){
  return a.x*b.x + a.y*b.y + a.z*b.z + a.w*b.w;
}
__device__ __forceinline__ float sigmoidf_(float z){ return 1.f/(1.f+__expf(-z)); }
__device__ __forceinline__ float4 fma4(float4 a, float4 w, float s){
  a.x += w.x*s; a.y += w.y*s; a.z += w.z*s; a.w += w.w*s; return a;
}
__device__ __forceinline__ float4 add4(float4 a, float4 b){
  a.x+=b.x; a.y+=b.y; a.z+=b.z; a.w+=b.w; return a;
}

// ---------------- fused pre: weight transposes + xl pad-zero + LN/left/right GEMM ----------------
__global__ void __launch_bounds__(512,2) k_pre(
    const float* __restrict__ Wo, const float* __restrict__ SW,
    const float* __restrict__ Wl, const float* __restrict__ Wq,
    const float* __restrict__ Wk, const float* __restrict__ Wv,
    const float* __restrict__ CW,
    float* __restrict__ Wot, float* __restrict__ SWt, float* __restrict__ WLt,
    float* __restrict__ Wqt, float* __restrict__ Wkt, float* __restrict__ Wvt,
    float* __restrict__ CWt,
    const float* __restrict__ x, const float* __restrict__ lg,
    const float* __restrict__ lb, const float* __restrict__ WL,
    const float* __restrict__ bL, const float* __restrict__ WR,
    const float* __restrict__ bR,
    const float* __restrict__ Wi, const float* __restrict__ bi,
    const float* __restrict__ Wf, const float* __restrict__ bf,
    float* __restrict__ xl, float* __restrict__ xr,
    float* __restrict__ ibp, float* __restrict__ fbp){
  __shared__ __align__(16) float smem[4224];   // 16,896 B
  int bid = blockIdx.x, tid = threadIdx.x;     // 512 thr
  if (bid < 208){
    if (bid==0){   // zero the 4 pad rows of each batch in padded xl
      float4 z = make_float4(0.f,0.f,0.f,0.f);
      for(int i=tid;i<2048;i+=512){
        int b4=i>>9, idx=i&511;
        ((float4*)xl)[(size_t)b4*(XLS/4) + idx] = z;
      }
    }
    float (*ts)[65] = (float(*)[65])smem;      // [64][65]
    const float* src; float* dst; int O,K,to,tk;
    if (bid<64){ src=Wo; dst=Wot; O=512;K=512; to=bid>>3; tk=bid&7; }
    else if (bid<128){ int r=bid-64; src=SW; dst=SWt; O=512;K=512; to=r>>3; tk=r&7; }
    else if (bid<160){ int r=bid-128; src=Wl; dst=WLt; O=256;K=512; to=r>>3; tk=r&7; }
    else {
      int r=bid-160; int m=r>>4; int rr=r&15; int h=rr>>2; int s=rr&3;
      src=(m==0?Wq:m==1?Wk:Wv) + h*16384;
      dst=(m==0?Wqt:m==1?Wkt:Wvt) + h*16384;
      O=128; K=128; to=s>>1; tk=s&1;
    }
    int lk=tid&63, ro=tid>>6;    // ro 0..7
    #pragma unroll
    for(int p=0;p<8;p++) ts[p*8+ro][lk] = src[(size_t)(to*64+p*8+ro)*K + tk*64+lk];
    __syncthreads();
    #pragma unroll
    for(int p=0;p<8;p++) dst[(size_t)(tk*64+p*8+ro)*O + to*64+lk] = ts[lk][p*8+ro];
  } else if (bid < 464){
    float4 (*t4)[33] = (float4(*)[33])smem;    // [32][33] float4
    int r = bid-208; int to=r>>4, tk=r&15;
    const float4* src4=(const float4*)CW; float4* dst4=(float4*)CWt;
    int li=tid&31, ro=tid>>5;    // ro 0..15
    #pragma unroll
    for(int p=0;p<2;p++) t4[p*16+ro][li] = src4[(size_t)(to*32+p*16+ro)*512 + tk*32+li];
    __syncthreads();
    #pragma unroll
    for(int p=0;p<2;p++) dst4[(size_t)(tk*32+p*16+ro)*512 + to*32+li] = t4[li][p*16+ro];
  } else {
    float (*xs)[Dz] = (float(*)[Dz])smem;      // [8][256] = 8KB
    float (*rif)[4][8] = (float(*)[4][8])(smem + 8*Dz);  // 64 floats
    int wbid = bid-464;
    int r0 = (wbid&127)*8; int oh = wbid>>7;
    int bb2 = r0>>8, tb2 = r0&255;             // batch / in-batch row for padded xl
    ((float4*)&xs[0][0])[tid] = ((const float4*)(x + (size_t)r0*Dz))[tid];
    __syncthreads();
    int w = tid>>6, lane = tid&63;
    float a0 = xs[w][lane],     a1 = xs[w][lane+64];
    float a2 = xs[w][lane+128], a3 = xs[w][lane+192];
    float s  = a0+a1+a2+a3;
    float s2 = a0*a0+a1*a1+a2*a2+a3*a3;
    #pragma unroll
    for (int off=1; off<64; off<<=1){ s += __shfl_xor(s, off); s2 += __shfl_xor(s2, off); }
    float mu = s*(1.f/Dz);
    float rs = rsqrtf(s2*(1.f/Dz)-mu*mu+1e-5f);
    xs[w][lane]     = (a0-mu)*rs*lg[lane]    +lb[lane];
    xs[w][lane+64]  = (a1-mu)*rs*lg[lane+64] +lb[lane+64];
    xs[w][lane+128] = (a2-mu)*rs*lg[lane+128]+lb[lane+128];
    xs[w][lane+192] = (a3-mu)*rs*lg[lane+192]+lb[lane+192];
    __syncthreads();
    int which = tid>>8;               // 0 -> WL (+i/f), 1 -> WR
    int o = oh*256 + (tid&255);
    float acc[8]={0,0,0,0,0,0,0,0};
    const float* WM = which ? WR : WL;
    const float4* wm4 = (const float4*)(WM + (size_t)o*Dz);
    #pragma unroll 2
    for (int k4=0;k4<Dz/4;k4++){
      float4 wv=wm4[k4];
      #pragma unroll
      for(int tt=0;tt<8;tt++) acc[tt] += dot4(wv, ((const float4*)xs[tt])[k4]);
    }
    if (which==0){
      float blv=bL[o], wi_o=Wi[o], wf_o=Wf[o];
      float pi[8], pf[8];
      #pragma unroll
      for(int tt=0;tt<8;tt++){
        float xlv = acc[tt]+blv;
        xl[(size_t)bb2*XLS + (size_t)(XLP+tb2+tt)*D2z + o] = xlv;
        pi[tt]=xlv*wi_o; pf[tt]=xlv*wf_o;
      }
      #pragma unroll
      for(int off=1;off<64;off<<=1){
        #pragma unroll
        for(int tt=0;tt<8;tt++){ pi[tt]+=__shfl_xor(pi[tt],off); pf[tt]+=__shfl_xor(pf[tt],off); }
      }
      if(lane==0){
        #pragma unroll
        for(int tt=0;tt<8;tt++){ rif[0][w][tt]=pi[tt]; rif[1][w][tt]=pf[tt]; }
      }
    } else {
      float brv=bR[o];
      #pragma unroll
      for(int tt=0;tt<8;tt++) xr[(size_t)(r0+tt)*D2z+o]=acc[tt]+brv;
    }
    __syncthreads();
    if(tid<16){
      int r=tid&7, which2=tid>>3;
      float sv=0.f;
      #pragma unroll
      for(int ww=0;ww<4;ww++) sv+=rif[which2][ww][r];
      float bias = (oh==0) ? (which2==0 ? bi[0] : bf[0]) : 0.f;
      (which2==0 ? ibp : fbp)[oh*BT + r0 + r] = sv + bias;
    }
  }
}

// ---------------- fused mid: conv (no staging, padded-xl broadcast reads) + wov + decay ----------------
// LDS = 17,408 B (conv red only). launch_bounds(256,2): VGPR free, no spills (R7 lesson).
__global__ void __launch_bounds__(256,2) k_mid(
    const float* __restrict__ xl, const float* __restrict__ CWt,
    const float* __restrict__ cb, float* __restrict__ xt,
    const float* __restrict__ Wot, const float* __restrict__ bo,
    const float* __restrict__ Wvt, float* __restrict__ og, float* __restrict__ vv,
    const float* __restrict__ ibp, const float* __restrict__ fbp,
    float* __restrict__ G, float* __restrict__ Mx){
  __shared__ __align__(16) float smem[4352];    // 17,408 B
  int bid = blockIdx.x, tid = threadIdx.x;      // 256 thr
  if (bid < 512){
    // ---------------- conv: direct broadcast x reads ----------------
    float (*red)[64][17] = (float(*)[64][17])smem;   // [4][64][17]
    int tile = bid&63, o0 = (bid>>6)*64;
    int b = tile>>4; int t0 = (tile&15)*16;
    int ol = tid&63, ch = tid>>6;
    int o = o0 + ol, ic0 = ch*128;
    // padded row for (t0-3+j) is (XLP + t0-3+j) = t0+1+j
    const float* xb = xl + (size_t)b*XLS + (size_t)(t0+1)*D2z + ic0;
    float acc[16];
    #pragma unroll
    for(int tt=0;tt<16;tt++) acc[tt]=0.f;
    const float4* w4 = (const float4*)CWt + o;   // quad index [i*512 + o]
    for(int i=0;i<128;i+=4){
      int ig = ic0+i;
      float4 w0=w4[(size_t)(ig+0)*512], w1=w4[(size_t)(ig+1)*512];
      float4 w2=w4[(size_t)(ig+2)*512], w3=w4[(size_t)(ig+3)*512];
      float4 xr4[19];
      #pragma unroll
      for(int j=0;j<19;j++) xr4[j]=*(const float4*)&xb[(size_t)j*D2z + i];
      #pragma unroll
      for(int tt=0;tt<16;tt++){
        acc[tt] += w0.x*xr4[tt].x + w0.y*xr4[tt+1].x + w0.z*xr4[tt+2].x + w0.w*xr4[tt+3].x
                 + w1.x*xr4[tt].y + w1.y*xr4[tt+1].y + w1.z*xr4[tt+2].y + w1.w*xr4[tt+3].y
                 + w2.x*xr4[tt].z + w2.y*xr4[tt+1].z + w2.z*xr4[tt+2].z + w2.w*xr4[tt+3].z
                 + w3.x*xr4[tt].w + w3.y*xr4[tt+1].w + w3.z*xr4[tt+2].w + w3.w*xr4[tt+3].w;
      }
    }
    #pragma unroll
    for(int tt=0;tt<16;tt++) red[ch][ol][tt]=acc[tt];
    __syncthreads();
    for(int idx=tid; idx<1024; idx+=256){
      int oo = idx&63, t = idx>>6;
      float y = red[0][oo][t]+red[1][oo][t]+red[2][oo][t]+red[3][oo][t] + cb[o0+oo];
      xt[(size_t)((b<<8)+t0+t)*D2z + o0+oo] = y*sigmoidf_(y);
    }
  } else if (bid < 1024){
    // ---------------- wov (direct broadcast x reads, two passes over one reduce buf) ----------------
    float4 (*red)[4][64] = (float4(*)[4][64])smem;    // 16KB
    int wbid = bid-512;
    int r0=(wbid&255)*4; int oh=wbid>>8;
    int b = r0>>8, trow = r0&255;
    const float* xp = xl + (size_t)b*XLS + (size_t)(XLP+trow)*D2z;
    int ol=tid&63, ch=tid>>6;
    // pass O: o-gate GEMM
    {
      float4 a0={0,0,0,0},a1={0,0,0,0},a2={0,0,0,0},a3={0,0,0,0};
      const float4* wp=(const float4*)Wot + (size_t)ch*16384 + (oh*64+ol);
      #pragma unroll 2
      for(int kq=0;kq<32;kq++){
        int k=ch*128+kq*4;
        float4 w0=wp[(kq*4+0)*128], w1=wp[(kq*4+1)*128], w2=wp[(kq*4+2)*128], w3=wp[(kq*4+3)*128];
        float4 x0=*(const float4*)&xp[k];
        float4 x1=*(const float4*)&xp[D2z+k];
        float4 x2=*(const float4*)&xp[2*D2z+k];
        float4 x3=*(const float4*)&xp[3*D2z+k];
        a0=fma4(fma4(fma4(fma4(a0,w0,x0.x),w1,x0.y),w2,x0.z),w3,x0.w);
        a1=fma4(fma4(fma4(fma4(a1,w0,x1.x),w1,x1.y),w2,x1.z),w3,x1.w);
        a2=fma4(fma4(fma4(fma4(a2,w0,x2.x),w1,x2.y),w2,x2.z),w3,x2.w);
        a3=fma4(fma4(fma4(fma4(a3,w0,x3.x),w1,x3.y),w2,x3.z),w3,x3.w);
      }
      red[ch][0][ol]=a0; red[ch][1][ol]=a1; red[ch][2][ol]=a2; red[ch][3][ol]=a3;
    }
    __syncthreads();
    {
      float4 s=add4(add4(red[0][ch][ol],red[1][ch][ol]),add4(red[2][ch][ol],red[3][ch][ol]));
      float4 bb=((const float4*)bo)[oh*64+ol];
      s.x=sigmoidf_(s.x+bb.x); s.y=sigmoidf_(s.y+bb.y);
      s.z=sigmoidf_(s.z+bb.z); s.w=sigmoidf_(s.w+bb.w);
      ((float4*)(og+(size_t)(r0+ch)*D2z))[oh*64+ol]=s;
    }
    __syncthreads();
    // pass V: block-diag v
    {
      int h = oh*2 + (ol>>5), odq = ol&31;
      float4 v0={0,0,0,0},v1={0,0,0,0},v2={0,0,0,0},v3={0,0,0,0};
      const float4* wv=(const float4*)Wvt + (size_t)h*4096 + (size_t)(ch*32)*32 + odq;
      int xoff = h*128 + ch*32;
      #pragma unroll 2
      for(int iq=0;iq<8;iq++){
        float4 w0=wv[(iq*4+0)*32], w1=wv[(iq*4+1)*32], w2=wv[(iq*4+2)*32], w3=wv[(iq*4+3)*32];
        int k=xoff+iq*4;
        float4 x0=*(const float4*)&xp[k];
        float4 x1=*(const float4*)&xp[D2z+k];
        float4 x2=*(const float4*)&xp[2*D2z+k];
        float4 x3=*(const float4*)&xp[3*D2z+k];
        v0=fma4(fma4(fma4(fma4(v0,w0,x0.x),w1,x0.y),w2,x0.z),w3,x0.w);
        v1=fma4(fma4(fma4(fma4(v1,w0,x1.x),w1,x1.y),w2,x1.z),w3,x1.w);
        v2=fma4(fma4(fma4(fma4(v2,w0,x2.x),w1,x2.y),w2,x2.z),w3,x2.w);
        v3=fma4(fma4(fma4(fma4(v3,w0,x3.x),w1,x3.y),w2,x3.z),w3,x3.w);
      }
      red[ch][0][ol]=v0; red[ch][1][ol]=v1; red[ch][2][ol]=v2; red[ch][3][ol]=v3;
    }
    __syncthreads();
    {
      float4 vs=add4(add4(red[0][ch][ol],red[1][ch][ol]),add4(red[2][ch][ol],red[3][ch][ol]));
      ((float4*)(vv+(size_t)(r0+ch)*D2z))[oh*64+ol]=vs;
    }
  } else {
    // ---------------- decay ----------------
    float* buf = smem;
    int b = bid-1024, t = tid;
    float f = fbp[b*Tz + t] + fbp[BT + b*Tz + t];
    float ibv = ibp[b*Tz + t] + ibp[BT + b*Tz + t];
    buf[t] = f; __syncthreads();
    float v = f;
    for (int off=1; off<Tz; off<<=1){
      float add = (t >= off) ? buf[t-off] : 0.f;
      __syncthreads();
      v += add; buf[t] = v;
      __syncthreads();
    }
    float F = v;
    float g = ibv - F;
    G[b*Tz+t] = g;
    buf[t] = g; __syncthreads();
    v = g;
    for (int off=1; off<Tz; off<<=1){
      float other = (t >= off) ? buf[t-off] : -3.4e38f;
      __syncthreads();
      v = fmaxf(v, other); buf[t] = v;
      __syncthreads();
    }
    Mx[b*Tz+t] = fmaxf(v, 0.f);
  }
}

// ---------------- q,k (block-diag) + skip GEMM: direct xt reads, 3 passes ----------------
__global__ void __launch_bounds__(256,2) k_qks(const float* __restrict__ xt,
    const float* __restrict__ SWt, const float* __restrict__ Wqt,
    const float* __restrict__ Wkt,
    float* __restrict__ qq, float* __restrict__ kk, float* __restrict__ sk){
  __shared__ __align__(16) float smem[4096];                // 16 KB
  float4 (*red)[4][64] = (float4(*)[4][64])smem;
  int r0=blockIdx.x*4; int oh=blockIdx.y; int tid=threadIdx.x;
  const float* xp = xt + (size_t)r0*D2z;
  int ol=tid&63, ch=tid>>6;
  // ---- pass S: skip GEMM ----
  {
    float4 s0={0,0,0,0},s1={0,0,0,0},s2={0,0,0,0},s3={0,0,0,0};
    const float4* wp=(const float4*)SWt + (size_t)ch*16384 + (oh*64+ol);
    #pragma unroll 2
    for(int kq=0;kq<32;kq++){
      int k=ch*128+kq*4;
      float4 w0=wp[(kq*4+0)*128], w1=wp[(kq*4+1)*128], w2=wp[(kq*4+2)*128], w3=wp[(kq*4+3)*128];
      float4 x0=*(const float4*)&xp[k];
      float4 x1=*(const float4*)&xp[D2z+k];
      float4 x2=*(const float4*)&xp[2*D2z+k];
      float4 x3=*(const float4*)&xp[3*D2z+k];
      s0=fma4(fma4(fma4(fma4(s0,w0,x0.x),w1,x0.y),w2,x0.z),w3,x0.w);
      s1=fma4(fma4(fma4(fma4(s1,w0,x1.x),w1,x1.y),w2,x1.z),w3,x1.w);
      s2=fma4(fma4(fma4(fma4(s2,w0,x2.x),w1,x2.y),w2,x2.z),w3,x2.w);
      s3=fma4(fma4(fma4(fma4(s3,w0,x3.x),w1,x3.y),w2,x3.z),w3,x3.w);
    }
    red[ch][0][ol]=s0; red[ch][1][ol]=s1; red[ch][2][ol]=s2; red[ch][3][ol]=s3;
  }
  __syncthreads();
  {
    float4 sv=add4(add4(red[0][ch][ol],red[1][ch][ol]),add4(red[2][ch][ol],red[3][ch][ol]));
    ((float4*)(sk+(size_t)(r0+ch)*D2z))[oh*64+ol]=sv;
  }
  __syncthreads();
  int h = oh*2 + (ol>>5), odq = ol&31;
  int xoff = h*128 + ch*32;
  // ---- pass Q ----
  {
    float4 q0={0,0,0,0},q1={0,0,0,0},q2={0,0,0,0},q3={0,0,0,0};
    const float4* wq=(const float4*)Wqt + (size_t)h*4096 + (size_t)(ch*32)*32 + odq;
    #pragma unroll 2
    for(int iq=0;iq<8;iq++){
      float4 w0=wq[(iq*4+0)*32], w1=wq[(iq*4+1)*32], w2=wq[(iq*4+2)*32], w3=wq[(iq*4+3)*32];
      int k=xoff+iq*4;
      float4 x0=*(const float4*)&xp[k];
      float4 x1=*(const float4*)&xp[D2z+k];
      float4 x2=*(const float4*)&xp[2*D2z+k];
      float4 x3=*(const float4*)&xp[3*D2z+k];
      q0=fma4(fma4(fma4(fma4(q0,w0,x0.x),w1,x0.y),w2,x0.z),w3,x0.w);
      q1=fma4(fma4(fma4(fma4(q1,w0,x1.x),w1,x1.y),w2,x1.z),w3,x1.w);
      q2=fma4(fma4(fma4(fma4(q2,w0,x2.x),w1,x2.y),w2,x2.z),w3,x2.w);
      q3=fma4(fma4(fma4(fma4(q3,w0,x3.x),w1,x3.y),w2,x3.z),w3,x3.w);
    }
    red[ch][0][ol]=q0; red[ch][1][ol]=q1; red[ch][2][ol]=q2; red[ch][3][ol]=q3;
  }
  __syncthreads();
  {
    float4 qv=add4(add4(red[0][ch][ol],red[1][ch][ol]),add4(red[2][ch][ol],red[3][ch][ol]));
    ((float4*)(qq+(size_t)(r0+ch)*D2z))[oh*64+ol]=qv;
  }
  __syncthreads();
  // ---- pass K ----
  {
    float4 k0={0,0,0,0},k1={0,0,0,0},k2={0,0,0,0},k3={0,0,0,0};
    const float4* wk=(const float4*)Wkt + (size_t)h*4096 + (size_t)(ch*32)*32 + odq;
    #pragma unroll 2
    for(int iq=0;iq<8;iq++){
      float4 w0=wk[(iq*4+0)*32], w1=wk[(iq*4+1)*32], w2=wk[(iq*4+2)*32], w3=wk[(iq*4+3)*32];
      int k=xoff+iq*4;
      float4 x0=*(const float4*)&xp[k];
      float4 x1=*(const float4*)&xp[D2z+k];
      float4 x2=*(const float4*)&xp[2*D2z+k];
      float4 x3=*(const float4*)&xp[3*D2z+k];
      k0=fma4(fma4(fma4(fma4(k0,w0,x0.x),w1,x0.y),w2,x0.z),w3,x0.w);
      k1=fma4(fma4(fma4(fma4(k1,w0,x1.x),w1,x1.y),w2,x1.z),w3,x1.w);
      k2=fma4(fma4(fma4(fma4(k2,w0,x2.x),w1,x2.y),w2,x2.z),w3,x2.w);
      k3=fma4(fma4(fma4(fma4(k3,w0,x3.x),w1,x3.y),w2,x3.z),w3,x3.w);
    }
    red[ch][0][ol]=k0; red[ch][1][ol]=k1; red[ch][2][ol]=k2; red[ch][3][ol]=k3;
  }
  __syncthreads();
  {
    float4 kv=add4(add4(red[0][ch][ol],red[1][ch][ol]),add4(red[2][ch][ol],red[3][ch][ol]));
    kv.x*=0.0625f; kv.y*=0.0625f; kv.z*=0.0625f; kv.w*=0.0625f;   // SCALE = D^-0.5
    ((float4*)(kk+(size_t)(r0+ch)*D2z))[oh*64+ol]=kv;
  }
}

// ---------------- scan as causal decayed attention + deterministic GN partials ----------------
#define TTa 4
__global__ void __launch_bounds__(256) k_attn(
    const float* __restrict__ qq, const float* __restrict__ kk,
    const float* __restrict__ vv, const float* __restrict__ og,
    const float* __restrict__ G, const float* __restrict__ Mx,
    float* __restrict__ hs, float* __restrict__ gnp){
  int b  = blockIdx.y;
  int t0 = blockIdx.x * TTa;
  int tid = threadIdx.x;            // 256
  __shared__ float Ps[TTa][Tz];     // 4KB (true cross-lane communication)
  __shared__ float inv_d[TTa];
  __shared__ float mxs[TTa];

  const float* qb = qq + ((size_t)b*Tz + t0)*D2z;   // broadcast-read directly
  if (tid < TTa) mxs[tid] = Mx[b*Tz + t0 + tid];
  __syncthreads();

  int s = tid;
  int smax = t0 + TTa - 1;
  {
    float acc[TTa] = {0,0,0,0};
    if (s <= smax){
      const float4* kp = (const float4*)(kk + ((size_t)b*Tz + s)*D2z);
      for (int k4=0; k4<D2z/4; k4++){
        float4 kv = kp[k4];
        #pragma unroll
        for (int tt=0; tt<TTa; tt++){
          float4 qv = *(const float4*)&qb[(size_t)tt*D2z + k4*4];
          acc[tt] += dot4(kv,qv);
        }
      }
    }
    float g = G[b*Tz + s];            // per-lane coalesced, read once
    #pragma unroll
    for (int tt=0; tt<TTa; tt++){
      int t = t0 + tt;
      Ps[tt][s] = (s <= t) ? acc[tt] * __expf(g - mxs[tt]) : 0.f;
    }
  }
  __syncthreads();
  {
    int wv = tid >> 6, lane = tid & 63;
    int tt = wv;
    float ssum = Ps[tt][lane] + Ps[tt][lane+64] + Ps[tt][lane+128] + Ps[tt][lane+192];
    #pragma unroll
    for (int off=1; off<64; off<<=1) ssum += __shfl_xor(ssum, off);
    if (lane==0) inv_d[tt] = 1.f / (fmaxf(fabsf(ssum), 1.f) + 1e-8f);
  }
  __syncthreads();
  {
    int c0 = tid, c1 = tid + 256;
    float a0[TTa]={0,0,0,0}, a1[TTa]={0,0,0,0};
    const float* vb = vv + (size_t)b*Tz*D2z;
    for (int s2=0; s2<=smax; s2+=4){
      float4 pr[TTa];
      #pragma unroll
      for (int tt=0; tt<TTa; tt++) pr[tt] = *(const float4*)&Ps[tt][s2];
      #pragma unroll
      for (int j=0; j<4; j++){
        int sj = s2 + j;
        float v0 = vb[(size_t)sj*D2z + c0];
        float v1 = vb[(size_t)sj*D2z + c1];
        #pragma unroll
        for (int tt=0; tt<TTa; tt++){
          float p = ((const float*)&pr[tt])[j];
          a0[tt] += p*v0; a1[tt] += p*v1;
        }
      }
    }
    float s0=0.f,q0=0.f,s1=0.f,q1=0.f;    // GN partials (c0-group, c1-group)
    #pragma unroll
    for (int tt=0; tt<TTa; tt++){
      size_t row = (size_t)b*Tz + t0 + tt;
      float id = inv_d[tt];
      float h0 = og[row*D2z + c0] * a0[tt] * id;
      float h1 = og[row*D2z + c1] * a1[tt] * id;
      hs[row*D2z + c0] = h0;
      hs[row*D2z + c1] = h1;
      s0+=h0; q0+=h0*h0; s1+=h1; q1+=h1*h1;
    }
    #pragma unroll
    for (int off=1; off<64; off<<=1){
      s0+=__shfl_xor(s0,off); q0+=__shfl_xor(q0,off);
      s1+=__shfl_xor(s1,off); q1+=__shfl_xor(q1,off);
    }
    if ((tid&63)==0){
      int wv=tid>>6, tile=blockIdx.x, half=wv&1;
      int g0=b*4+(wv>>1), g1=b*4+2+(wv>>1);
      float* p0 = gnp + ((size_t)(g0*64+tile)*2+half)*2;
      p0[0]=s0; p0[1]=q0;
      float* p1 = gnp + ((size_t)(g1*64+tile)*2+half)*2;
      p1[0]=s1; p1[1]=q1;
    }
  }
}

// ---------------- finish: GN stats from partials + apply + skip + swish-gate + W_last + residual ----------------
__global__ void __launch_bounds__(512,2) k_final(const float* __restrict__ hs,
    const float* __restrict__ gnp,
    const float* __restrict__ gng, const float* __restrict__ gnb,
    const float* __restrict__ sk, const float* __restrict__ xr,
    const float* __restrict__ WLt, const float* __restrict__ bl,
    const float* __restrict__ x, float* __restrict__ out){
  __shared__ __align__(16) float smem[8192];   // 32KB union
  __shared__ float ls[16];
  __shared__ float gst[8];                     // mu[4], rs[4]
  int r0=blockIdx.x*4; int b=r0>>8; int tid=threadIdx.x;  // 512
  {
    int w=tid>>6, lane=tid&63;
    int g=b*4+(w>>1), half=w&1;
    const float* p = gnp + ((size_t)(g*64+lane)*2 + half)*2;
    float s=p[0], q=p[1];
    #pragma unroll
    for(int off=1;off<64;off<<=1){ s+=__shfl_xor(s,off); q+=__shfl_xor(q,off); }
    if(lane==0){ ls[w*2]=s; ls[w*2+1]=q; }
  }
  __syncthreads();
  if(tid<4){
    float S = ls[4*tid]   + ls[4*tid+2];
    float S2= ls[4*tid+1] + ls[4*tid+3];
    float mu=S*(1.f/(Tz*DHz));
    float var=S2*(1.f/(Tz*DHz))-mu*mu;
    gst[tid]=mu; gst[4+tid]=rsqrtf(fmaxf(var,0.f)+1e-5f);
  }
  __syncthreads();
  float (*hm)[D2z] = (float(*)[D2z])smem;
  for(int idx=tid;idx<4*D2z;idx+=512){
    int tt=idx>>9,c=idx&511;
    size_t row=r0+tt;
    int gl=c>>7;
    float v=hs[row*D2z+c];
    float hg=(v-gst[gl])*gst[4+gl]*gng[c]+gnb[c]+sk[row*D2z+c];
    float xv=xr[row*D2z+c];
    hm[tt][c]=hg*(xv*sigmoidf_(xv));
  }
  __syncthreads();
  int ol=tid&63, ch=tid>>6;   // ch 0..7, k in [ch*64, ch*64+64)
  float4 a0={0,0,0,0},a1={0,0,0,0},a2={0,0,0,0},a3={0,0,0,0};
  const float4* wp=(const float4*)WLt + (size_t)(ch*64)*64 + ol;
  #pragma unroll 2
  for(int kq=0;kq<16;kq++){
    int k=ch*64+kq*4;
    float4 w0=wp[(kq*4+0)*64], w1=wp[(kq*4+1)*64], w2=wp[(kq*4+2)*64], w3=wp[(kq*4+3)*64];
    float4 x0=*(const float4*)&hm[0][k];
    float4 x1=*(const float4*)&hm[1][k];
    float4 x2=*(const float4*)&hm[2][k];
    float4 x3=*(const float4*)&hm[3][k];
    a0=fma4(fma4(fma4(fma4(a0,w0,x0.x),w1,x0.y),w2,x0.z),w3,x0.w);
    a1=fma4(fma4(fma4(fma4(a1,w0,x1.x),w1,x1.y),w2,x1.z),w3,x1.w);
    a2=fma4(fma4(fma4(fma4(a2,w0,x2.x),w1,x2.y),w2,x2.z),w3,x2.w);
    a3=fma4(fma4(fma4(fma4(a3,w0,x3.x),w1,x3.y),w2,x3.z),w3,x3.w);
  }
  __syncthreads();                 // hm dead -> alias red
  float4 (*red)[4][64] = (float4(*)[4][64])smem;   // [8][4][64] float4 = 32KB
  red[ch][0][ol]=a0; red[ch][1][ol]=a1; red[ch][2][ol]=a2; red[ch][3][ol]=a3;
  __syncthreads();
  if(tid<256){
    int tt=tid>>6, oo=tid&63;
    float4 sv={0,0,0,0};
    #pragma unroll
    for(int c2=0;c2<8;c2++) sv=add4(sv,red[c2][tt][oo]);
    float4 bb=((const float4*)bl)[oo];
    float4 xv=((const float4*)(x+(size_t)(r0+tt)*Dz))[oo];
    sv.x+=bb.x+xv.x; sv.y+=bb.y+xv.y; sv.z+=bb.z+xv.z; sv.w+=bb.w+xv.w;
    ((float4*)(out+(size_t)(r0+tt)*Dz))[oo]=sv;
  }
}

extern "C" void kernel_launch(void* const* d_in, const int* in_sizes, int n_in,
                              void* d_out, int out_size, void* d_ws, size_t ws_size,
                              hipStream_t stream) {
  (void)in_sizes; (void)n_in; (void)out_size; (void)ws_size;
  const float* x      = (const float*)d_in[0];
  const float* ln_g   = (const float*)d_in[1];
  const float* ln_b   = (const float*)d_in[2];
  const float* W_left = (const float*)d_in[3];
  const float* b_left = (const float*)d_in[4];
  const float* W_right= (const float*)d_in[5];
  const float* b_right= (const float*)d_in[6];
  const float* Wi     = (const float*)d_in[7];
  const float* bi     = (const float*)d_in[8];
  const float* Wf     = (const float*)d_in[9];
  const float* bf     = (const float*)d_in[10];
  const float* Wo     = (const float*)d_in[11];
  const float* bo     = (const float*)d_in[12];
  const float* Wq     = (const float*)d_in[13];
  const float* Wk     = (const float*)d_in[14];
  const float* Wv     = (const float*)d_in[15];
  const float* conv_w = (const float*)d_in[16];
  const float* conv_b = (const float*)d_in[17];
  const float* skip_W = (const float*)d_in[18];
  const float* gn_g   = (const float*)d_in[19];
  const float* gn_b   = (const float*)d_in[20];
  const float* W_last = (const float*)d_in[21];
  const float* b_last = (const float*)d_in[22];
  float* out = (float*)d_out;

  float* ws = (float*)d_ws;
  float* Wot  = ws;                  // 262144
  float* xl   = ws + 262144;         // 532480 (padded: 4 x 260 x 512)
  float* xr   = ws + 794624;         // 524288
  float* xt   = ws + 1318912;        // 524288
  float* og   = ws + 1843200;        // 524288
  float* vv   = ws + 2367488;        // 524288
  float* qq   = ws + 2891776;        // 524288
  float* kk   = ws + 3416064;        // 524288
  float* sk   = ws + 3940352;        // 524288
  float* hs   = ws + 4464640;        // 524288
  float* ibp  = ws + 4988928;        // 2048
  float* fbp  = ws + 4990976;        // 2048
  float* Gd   = ws + 4993024;        // 1024
  float* Mxd  = ws + 4994048;        // 1024
  float* SWt  = ws + 4995072;        // 262144
  float* WLt  = ws + 5257216;        // 131072
  float* Wqt  = ws + 5388288;        // 65536
  float* Wkt  = ws + 5453824;        // 65536
  float* Wvt  = ws + 5519360;        // 65536
  float* CWt  = ws + 5584896;        // 1048576
  float* gnp  = ws + 6633472;        // 4096

  k_pre   <<<720, 512, 0, stream>>>(Wo, skip_W, W_last, Wq, Wk, Wv, conv_w,
                                    Wot, SWt, WLt, Wqt, Wkt, Wvt, CWt,
                                    x, ln_g, ln_b, W_left, b_left, W_right, b_right,
                                    Wi, bi, Wf, bf, xl, xr, ibp, fbp);
  k_mid   <<<1028, 256, 0, stream>>>(xl, CWt, conv_b, xt, Wot, bo, Wvt, og, vv,
                                     ibp, fbp, Gd, Mxd);
  k_qks   <<<dim3(BT/4, 2), 256, 0, stream>>>(xt, SWt, Wqt, Wkt, qq, kk, sk);
  k_attn  <<<dim3(Tz/TTa, Bz), 256, 0, stream>>>(qq, kk, vv, og, Gd, Mxd, hs, gnp);
  k_final <<<BT/4, 512, 0, stream>>>(hs, gnp, gn_g, gn_b, sk, xr, WLt, b_last, x, out);
}

// Round 13
// 158.997 us; speedup vs baseline: 1.1284x; 1.1284x over previous
//
#include <hip/hip_runtime.h>
#include <hip/hip_bf16.h>
#include <cstdint>

// Sizes
#define Bz 4
#define Tz 256
#define Dz 256
#define D2z 512
#define Hz 4
#define DHz 128
#define BT (Bz*Tz)          // 1024 rows

__device__ __forceinline__ float dot4(float4 a, float4 b){
  return a.x*b.x + a.y*b.y + a.z*b.z + a.w*b.w;
}
__device__ __forceinline__ float sigmoidf_(float z){ return 1.f/(1.f+__expf(-z)); }
__device__ __forceinline__ float4 fma4(float4 a, float4 w, float s){
  a.x += w.x*s; a.y += w.y*s; a.z += w.z*s; a.w += w.w*s; return a;
}
__device__ __forceinline__ float4 add4(float4 a, float4 b){
  a.x+=b.x; a.y+=b.y; a.z+=b.z; a.w+=b.w; return a;
}

// ---------------- fused pre: weight transposes (independent) + LN/left/right GEMM ----------------
__global__ void __launch_bounds__(512,2) k_pre(
    const float* __restrict__ Wo, const float* __restrict__ SW,
    const float* __restrict__ Wl, const float* __restrict__ Wq,
    const float* __restrict__ Wk, const float* __restrict__ Wv,
    const float* __restrict__ CW,
    float* __restrict__ Wot, float* __restrict__ SWt, float* __restrict__ WLt,
    float* __restrict__ Wqt, float* __restrict__ Wkt, float* __restrict__ Wvt,
    float* __restrict__ CWt,
    const float* __restrict__ x, const float* __restrict__ lg,
    const float* __restrict__ lb, const float* __restrict__ WL,
    const float* __restrict__ bL, const float* __restrict__ WR,
    const float* __restrict__ bR,
    const float* __restrict__ Wi, const float* __restrict__ bi,
    const float* __restrict__ Wf, const float* __restrict__ bf,
    float* __restrict__ xl, float* __restrict__ xr,
    float* __restrict__ ibp, float* __restrict__ fbp){
  __shared__ __align__(16) float smem[4224];   // 16,896 B
  int bid = blockIdx.x, tid = threadIdx.x;     // 512 thr
  if (bid < 208){
    float (*ts)[65] = (float(*)[65])smem;      // [64][65]
    const float* src; float* dst; int O,K,to,tk;
    if (bid<64){ src=Wo; dst=Wot; O=512;K=512; to=bid>>3; tk=bid&7; }
    else if (bid<128){ int r=bid-64; src=SW; dst=SWt; O=512;K=512; to=r>>3; tk=r&7; }
    else if (bid<160){ int r=bid-128; src=Wl; dst=WLt; O=256;K=512; to=r>>3; tk=r&7; }
    else {
      int r=bid-160; int m=r>>4; int rr=r&15; int h=rr>>2; int s=rr&3;
      src=(m==0?Wq:m==1?Wk:Wv) + h*16384;
      dst=(m==0?Wqt:m==1?Wkt:Wvt) + h*16384;
      O=128; K=128; to=s>>1; tk=s&1;
    }
    int lk=tid&63, ro=tid>>6;    // ro 0..7
    #pragma unroll
    for(int p=0;p<8;p++) ts[p*8+ro][lk] = src[(size_t)(to*64+p*8+ro)*K + tk*64+lk];
    __syncthreads();
    #pragma unroll
    for(int p=0;p<8;p++) dst[(size_t)(tk*64+p*8+ro)*O + to*64+lk] = ts[lk][p*8+ro];
  } else if (bid < 464){
    float4 (*t4)[33] = (float4(*)[33])smem;    // [32][33] float4
    int r = bid-208; int to=r>>4, tk=r&15;
    const float4* src4=(const float4*)CW; float4* dst4=(float4*)CWt;
    int li=tid&31, ro=tid>>5;    // ro 0..15
    #pragma unroll
    for(int p=0;p<2;p++) t4[p*16+ro][li] = src4[(size_t)(to*32+p*16+ro)*512 + tk*32+li];
    __syncthreads();
    #pragma unroll
    for(int p=0;p<2;p++) dst4[(size_t)(tk*32+p*16+ro)*512 + to*32+li] = t4[li][p*16+ro];
  } else {
    float (*xs)[Dz] = (float(*)[Dz])smem;      // [8][256] = 8KB
    float (*rif)[4][8] = (float(*)[4][8])(smem + 8*Dz);  // 64 floats
    int wbid = bid-464;
    int r0 = (wbid&127)*8; int oh = wbid>>7;
    ((float4*)&xs[0][0])[tid] = ((const float4*)(x + (size_t)r0*Dz))[tid];
    __syncthreads();
    int w = tid>>6, lane = tid&63;
    float a0 = xs[w][lane],     a1 = xs[w][lane+64];
    float a2 = xs[w][lane+128], a3 = xs[w][lane+192];
    float s  = a0+a1+a2+a3;
    float s2 = a0*a0+a1*a1+a2*a2+a3*a3;
    #pragma unroll
    for (int off=1; off<64; off<<=1){ s += __shfl_xor(s, off); s2 += __shfl_xor(s2, off); }
    float mu = s*(1.f/Dz);
    float rs = rsqrtf(s2*(1.f/Dz)-mu*mu+1e-5f);
    xs[w][lane]     = (a0-mu)*rs*lg[lane]    +lb[lane];
    xs[w][lane+64]  = (a1-mu)*rs*lg[lane+64] +lb[lane+64];
    xs[w][lane+128] = (a2-mu)*rs*lg[lane+128]+lb[lane+128];
    xs[w][lane+192] = (a3-mu)*rs*lg[lane+192]+lb[lane+192];
    __syncthreads();
    int which = tid>>8;               // 0 -> WL (+i/f), 1 -> WR
    int o = oh*256 + (tid&255);
    float acc[8]={0,0,0,0,0,0,0,0};
    const float* WM = which ? WR : WL;
    const float4* wm4 = (const float4*)(WM + (size_t)o*Dz);
    #pragma unroll 2
    for (int k4=0;k4<Dz/4;k4++){
      float4 wv=wm4[k4];
      #pragma unroll
      for(int tt=0;tt<8;tt++) acc[tt] += dot4(wv, ((const float4*)xs[tt])[k4]);
    }
    if (which==0){
      float blv=bL[o], wi_o=Wi[o], wf_o=Wf[o];
      float pi[8], pf[8];
      #pragma unroll
      for(int tt=0;tt<8;tt++){
        float xlv = acc[tt]+blv;
        xl[(size_t)(r0+tt)*D2z+o]=xlv;
        pi[tt]=xlv*wi_o; pf[tt]=xlv*wf_o;
      }
      #pragma unroll
      for(int off=1;off<64;off<<=1){
        #pragma unroll
        for(int tt=0;tt<8;tt++){ pi[tt]+=__shfl_xor(pi[tt],off); pf[tt]+=__shfl_xor(pf[tt],off); }
      }
      if(lane==0){
        #pragma unroll
        for(int tt=0;tt<8;tt++){ rif[0][w][tt]=pi[tt]; rif[1][w][tt]=pf[tt]; }
      }
    } else {
      float brv=bR[o];
      #pragma unroll
      for(int tt=0;tt<8;tt++) xr[(size_t)(r0+tt)*D2z+o]=acc[tt]+brv;
    }
    __syncthreads();
    if(tid<16){
      int r=tid&7, which2=tid>>3;
      float sv=0.f;
      #pragma unroll
      for(int ww=0;ww<4;ww++) sv+=rif[which2][ww][r];
      float bias = (oh==0) ? (which2==0 ? bi[0] : bf[0]) : 0.f;
      (which2==0 ? ibp : fbp)[oh*BT + r0 + r] = sv + bias;
    }
  }
}

// ---------------- fused mid: conv (1024 blocks: 64 tiles x 32-out groups) + wov + decay ----------------
// Grid 1540 > ~1024 residency slots -> refill; conv/wov per-block work near-balanced
// (1.05M vs 0.65M MAC). LDS 38,912 B; launch_bounds(256,2) keeps VGPRs free (R7: no spills).
__global__ void __launch_bounds__(256,2) k_mid(
    const float* __restrict__ xl, const float* __restrict__ CWt,
    const float* __restrict__ cb, float* __restrict__ xt,
    const float* __restrict__ Wot, const float* __restrict__ bo,
    const float* __restrict__ Wvt, float* __restrict__ og, float* __restrict__ vv,
    const float* __restrict__ ibp, const float* __restrict__ fbp,
    float* __restrict__ G, float* __restrict__ Mx){
  __shared__ __align__(16) float smem[9728];    // 38,912 B
  int bid = blockIdx.x, tid = threadIdx.x;      // 256 thr
  if (bid < 1024){
    // ---------------- conv: t-tile 16, 32-out group, 8 ic-chunks of 64 ----------------
    float (*xs)[D2z] = (float(*)[D2z])smem;     // [19][512] = 38,912 B
    int tile = bid&63, o0 = (bid>>6)*32;        // 16 o-groups of 32
    int b = tile>>4; int t0 = (tile&15)*16;
    for(int idx=tid; idx<19*(D2z/4); idx+=256){
      int j = idx>>7, k4 = idx&127;
      int t = t0-3+j;
      float4 v = (t>=0) ? ((const float4*)(xl + (size_t)((b<<8)+t)*D2z))[k4]
                        : make_float4(0.f,0.f,0.f,0.f);
      ((float4*)xs[j])[k4]=v;
    }
    __syncthreads();
    int ol = tid&31, ch = tid>>5;               // 32 outs x 8 chunks
    int o = o0 + ol, ic0 = ch*64;
    float acc[16];
    #pragma unroll
    for(int tt=0;tt<16;tt++) acc[tt]=0.f;
    const float4* w4 = (const float4*)CWt + o;  // quad index [i*512 + o]
    for(int i=0;i<64;i+=4){
      int ig = ic0+i;
      float4 w0=w4[(size_t)(ig+0)*512], w1=w4[(size_t)(ig+1)*512];
      float4 w2=w4[(size_t)(ig+2)*512], w3=w4[(size_t)(ig+3)*512];
      float4 xr4[19];
      #pragma unroll
      for(int j=0;j<19;j++) xr4[j]=*(const float4*)&xs[j][ig];
      #pragma unroll
      for(int tt=0;tt<16;tt++){
        acc[tt] += w0.x*xr4[tt].x + w0.y*xr4[tt+1].x + w0.z*xr4[tt+2].x + w0.w*xr4[tt+3].x
                 + w1.x*xr4[tt].y + w1.y*xr4[tt+1].y + w1.z*xr4[tt+2].y + w1.w*xr4[tt+3].y
                 + w2.x*xr4[tt].z + w2.y*xr4[tt+1].z + w2.z*xr4[tt+2].z + w2.w*xr4[tt+3].z
                 + w3.x*xr4[tt].w + w3.y*xr4[tt+1].w + w3.z*xr4[tt+2].w + w3.w*xr4[tt+3].w;
      }
    }
    __syncthreads();                            // xs dead; alias red onto it
    float (*red)[32][17] = (float(*)[32][17])smem;   // [8][32][17] = 17,408 B
    #pragma unroll
    for(int tt=0;tt<16;tt++) red[ch][ol][tt]=acc[tt];
    __syncthreads();
    for(int idx=tid; idx<512; idx+=256){
      int oo = idx&31, t = idx>>5;
      float y = red[0][oo][t]+red[1][oo][t]+red[2][oo][t]+red[3][oo][t]
              + red[4][oo][t]+red[5][oo][t]+red[6][oo][t]+red[7][oo][t] + cb[o0+oo];
      xt[(size_t)((b<<8)+t0+t)*D2z + o0+oo] = y*sigmoidf_(y);
    }
  } else if (bid < 1536){
    // ---------------- wov (two-pass over one reduce buffer) ----------------
    float (*xs)[D2z] = (float(*)[D2z])smem;                    // [4][512] 8KB
    float4 (*red)[4][64] = (float4(*)[4][64])(smem + 2048);    // 16KB
    int wbid = bid-1024;
    int r0=(wbid&255)*4; int oh=wbid>>8;
    for(int idx=tid;idx<512;idx+=256)
      ((float4*)&xs[0][0])[idx]=((const float4*)(xl+(size_t)r0*D2z))[idx];
    __syncthreads();
    int ol=tid&63, ch=tid>>6;
    // pass O: o-gate GEMM
    {
      float4 a0={0,0,0,0},a1={0,0,0,0},a2={0,0,0,0},a3={0,0,0,0};
      const float4* wp=(const float4*)Wot + (size_t)ch*16384 + (oh*64+ol);
      #pragma unroll 2
      for(int kq=0;kq<32;kq++){
        int k=ch*128+kq*4;
        float4 w0=wp[(kq*4+0)*128], w1=wp[(kq*4+1)*128], w2=wp[(kq*4+2)*128], w3=wp[(kq*4+3)*128];
        float4 x0=*(const float4*)&xs[0][k];
        float4 x1=*(const float4*)&xs[1][k];
        float4 x2=*(const float4*)&xs[2][k];
        float4 x3=*(const float4*)&xs[3][k];
        a0=fma4(fma4(fma4(fma4(a0,w0,x0.x),w1,x0.y),w2,x0.z),w3,x0.w);
        a1=fma4(fma4(fma4(fma4(a1,w0,x1.x),w1,x1.y),w2,x1.z),w3,x1.w);
        a2=fma4(fma4(fma4(fma4(a2,w0,x2.x),w1,x2.y),w2,x2.z),w3,x2.w);
        a3=fma4(fma4(fma4(fma4(a3,w0,x3.x),w1,x3.y),w2,x3.z),w3,x3.w);
      }
      red[ch][0][ol]=a0; red[ch][1][ol]=a1; red[ch][2][ol]=a2; red[ch][3][ol]=a3;
    }
    __syncthreads();
    {
      float4 s=add4(add4(red[0][ch][ol],red[1][ch][ol]),add4(red[2][ch][ol],red[3][ch][ol]));
      float4 bb=((const float4*)bo)[oh*64+ol];
      s.x=sigmoidf_(s.x+bb.x); s.y=sigmoidf_(s.y+bb.y);
      s.z=sigmoidf_(s.z+bb.z); s.w=sigmoidf_(s.w+bb.w);
      ((float4*)(og+(size_t)(r0+ch)*D2z))[oh*64+ol]=s;
    }
    __syncthreads();
    // pass V: block-diag v
    {
      int h = oh*2 + (ol>>5), odq = ol&31;
      float4 v0={0,0,0,0},v1={0,0,0,0},v2={0,0,0,0},v3={0,0,0,0};
      const float4* wv=(const float4*)Wvt + (size_t)h*4096 + (size_t)(ch*32)*32 + odq;
      int xoff = h*128 + ch*32;
      #pragma unroll 2
      for(int iq=0;iq<8;iq++){
        float4 w0=wv[(iq*4+0)*32], w1=wv[(iq*4+1)*32], w2=wv[(iq*4+2)*32], w3=wv[(iq*4+3)*32];
        float4 x0=*(const float4*)&xs[0][xoff+iq*4];
        float4 x1=*(const float4*)&xs[1][xoff+iq*4];
        float4 x2=*(const float4*)&xs[2][xoff+iq*4];
        float4 x3=*(const float4*)&xs[3][xoff+iq*4];
        v0=fma4(fma4(fma4(fma4(v0,w0,x0.x),w1,x0.y),w2,x0.z),w3,x0.w);
        v1=fma4(fma4(fma4(fma4(v1,w0,x1.x),w1,x1.y),w2,x1.z),w3,x1.w);
        v2=fma4(fma4(fma4(fma4(v2,w0,x2.x),w1,x2.y),w2,x2.z),w3,x2.w);
        v3=fma4(fma4(fma4(fma4(v3,w0,x3.x),w1,x3.y),w2,x3.z),w3,x3.w);
      }
      red[ch][0][ol]=v0; red[ch][1][ol]=v1; red[ch][2][ol]=v2; red[ch][3][ol]=v3;
    }
    __syncthreads();
    {
      float4 vs=add4(add4(red[0][ch][ol],red[1][ch][ol]),add4(red[2][ch][ol],red[3][ch][ol]));
      ((float4*)(vv+(size_t)(r0+ch)*D2z))[oh*64+ol]=vs;
    }
  } else {
    // ---------------- decay ----------------
    float* buf = smem;
    int b = bid-1536, t = tid;
    float f = fbp[b*Tz + t] + fbp[BT + b*Tz + t];
    float ibv = ibp[b*Tz + t] + ibp[BT + b*Tz + t];
    buf[t] = f; __syncthreads();
    float v = f;
    for (int off=1; off<Tz; off<<=1){
      float add = (t >= off) ? buf[t-off] : 0.f;
      __syncthreads();
      v += add; buf[t] = v;
      __syncthreads();
    }
    float F = v;
    float g = ibv - F;
    G[b*Tz+t] = g;
    buf[t] = g; __syncthreads();
    v = g;
    for (int off=1; off<Tz; off<<=1){
      float other = (t >= off) ? buf[t-off] : -3.4e38f;
      __syncthreads();
      v = fmaxf(v, other); buf[t] = v;
      __syncthreads();
    }
    Mx[b*Tz+t] = fmaxf(v, 0.f);
  }
}

// ---------------- q,k (block-diag) + skip GEMM: three passes over one reduce buffer ----------------
__global__ void __launch_bounds__(256,2) k_qks(const float* __restrict__ xt,
    const float* __restrict__ SWt, const float* __restrict__ Wqt,
    const float* __restrict__ Wkt,
    float* __restrict__ qq, float* __restrict__ kk, float* __restrict__ sk){
  __shared__ __align__(16) float smem[6144];                // 24,576 B
  float (*xs)[D2z] = (float(*)[D2z])smem;                   // 8KB
  float4 (*red)[4][64] = (float4(*)[4][64])(smem + 2048);   // 16KB
  int r0=blockIdx.x*4; int oh=blockIdx.y; int tid=threadIdx.x;
  for(int idx=tid;idx<512;idx+=256)
    ((float4*)&xs[0][0])[idx]=((const float4*)(xt+(size_t)r0*D2z))[idx];
  __syncthreads();
  int ol=tid&63, ch=tid>>6;
  // ---- pass S: skip GEMM ----
  {
    float4 s0={0,0,0,0},s1={0,0,0,0},s2={0,0,0,0},s3={0,0,0,0};
    const float4* wp=(const float4*)SWt + (size_t)ch*16384 + (oh*64+ol);
    #pragma unroll 2
    for(int kq=0;kq<32;kq++){
      int k=ch*128+kq*4;
      float4 w0=wp[(kq*4+0)*128], w1=wp[(kq*4+1)*128], w2=wp[(kq*4+2)*128], w3=wp[(kq*4+3)*128];
      float4 x0=*(const float4*)&xs[0][k];
      float4 x1=*(const float4*)&xs[1][k];
      float4 x2=*(const float4*)&xs[2][k];
      float4 x3=*(const float4*)&xs[3][k];
      s0=fma4(fma4(fma4(fma4(s0,w0,x0.x),w1,x0.y),w2,x0.z),w3,x0.w);
      s1=fma4(fma4(fma4(fma4(s1,w0,x1.x),w1,x1.y),w2,x1.z),w3,x1.w);
      s2=fma4(fma4(fma4(fma4(s2,w0,x2.x),w1,x2.y),w2,x2.z),w3,x2.w);
      s3=fma4(fma4(fma4(fma4(s3,w0,x3.x),w1,x3.y),w2,x3.z),w3,x3.w);
    }
    red[ch][0][ol]=s0; red[ch][1][ol]=s1; red[ch][2][ol]=s2; red[ch][3][ol]=s3;
  }
  __syncthreads();
  {
    float4 sv=add4(add4(red[0][ch][ol],red[1][ch][ol]),add4(red[2][ch][ol],red[3][ch][ol]));
    ((float4*)(sk+(size_t)(r0+ch)*D2z))[oh*64+ol]=sv;
  }
  __syncthreads();
  int h = oh*2 + (ol>>5), odq = ol&31;
  int xoff = h*128 + ch*32;
  // ---- pass Q ----
  {
    float4 q0={0,0,0,0},q1={0,0,0,0},q2={0,0,0,0},q3={0,0,0,0};
    const float4* wq=(const float4*)Wqt + (size_t)h*4096 + (size_t)(ch*32)*32 + odq;
    #pragma unroll 2
    for(int iq=0;iq<8;iq++){
      float4 w0=wq[(iq*4+0)*32], w1=wq[(iq*4+1)*32], w2=wq[(iq*4+2)*32], w3=wq[(iq*4+3)*32];
      float4 x0=*(const float4*)&xs[0][xoff+iq*4];
      float4 x1=*(const float4*)&xs[1][xoff+iq*4];
      float4 x2=*(const float4*)&xs[2][xoff+iq*4];
      float4 x3=*(const float4*)&xs[3][xoff+iq*4];
      q0=fma4(fma4(fma4(fma4(q0,w0,x0.x),w1,x0.y),w2,x0.z),w3,x0.w);
      q1=fma4(fma4(fma4(fma4(q1,w0,x1.x),w1,x1.y),w2,x1.z),w3,x1.w);
      q2=fma4(fma4(fma4(fma4(q2,w0,x2.x),w1,x2.y),w2,x2.z),w3,x2.w);
      q3=fma4(fma4(fma4(fma4(q3,w0,x3.x),w1,x3.y),w2,x3.z),w3,x3.w);
    }
    red[ch][0][ol]=q0; red[ch][1][ol]=q1; red[ch][2][ol]=q2; red[ch][3][ol]=q3;
  }
  __syncthreads();
  {
    float4 qv=add4(add4(red[0][ch][ol],red[1][ch][ol]),add4(red[2][ch][ol],red[3][ch][ol]));
    ((float4*)(qq+(size_t)(r0+ch)*D2z))[oh*64+ol]=qv;
  }
  __syncthreads();
  // ---- pass K ----
  {
    float4 k0={0,0,0,0},k1={0,0,0,0},k2={0,0,0,0},k3={0,0,0,0};
    const float4* wk=(const float4*)Wkt + (size_t)h*4096 + (size_t)(ch*32)*32 + odq;
    #pragma unroll 2
    for(int iq=0;iq<8;iq++){
      float4 w0=wk[(iq*4+0)*32], w1=wk[(iq*4+1)*32], w2=wk[(iq*4+2)*32], w3=wk[(iq*4+3)*32];
      float4 x0=*(const float4*)&xs[0][xoff+iq*4];
      float4 x1=*(const float4*)&xs[1][xoff+iq*4];
      float4 x2=*(const float4*)&xs[2][xoff+iq*4];
      float4 x3=*(const float4*)&xs[3][xoff+iq*4];
      k0=fma4(fma4(fma4(fma4(k0,w0,x0.x),w1,x0.y),w2,x0.z),w3,x0.w);
      k1=fma4(fma4(fma4(fma4(k1,w0,x1.x),w1,x1.y),w2,x1.z),w3,x1.w);
      k2=fma4(fma4(fma4(fma4(k2,w0,x2.x),w1,x2.y),w2,x2.z),w3,x2.w);
      k3=fma4(fma4(fma4(fma4(k3,w0,x3.x),w1,x3.y),w2,x3.z),w3,x3.w);
    }
    red[ch][0][ol]=k0; red[ch][1][ol]=k1; red[ch][2][ol]=k2; red[ch][3][ol]=k3;
  }
  __syncthreads();
  {
    float4 kv=add4(add4(red[0][ch][ol],red[1][ch][ol]),add4(red[2][ch][ol],red[3][ch][ol]));
    kv.x*=0.0625f; kv.y*=0.0625f; kv.z*=0.0625f; kv.w*=0.0625f;   // SCALE = D^-0.5
    ((float4*)(kk+(size_t)(r0+ch)*D2z))[oh*64+ol]=kv;
  }
}

// ---------------- scan as causal decayed attention + deterministic GN partials ----------------
// gnp layout: [group g (16)][tile (64)][half (2)][2: sum, sumsq] — each slot written by
// exactly one wave of one block (no atomics, no RMW -> bitwise deterministic).
#define TTa 4
__global__ void __launch_bounds__(256) k_attn(
    const float* __restrict__ qq, const float* __restrict__ kk,
    const float* __restrict__ vv, const float* __restrict__ og,
    const float* __restrict__ G, const float* __restrict__ Mx,
    float* __restrict__ hs, float* __restrict__ gnp){
  int b  = blockIdx.y;
  int t0 = blockIdx.x * TTa;
  int tid = threadIdx.x;            // 256
  __shared__ float Qs[TTa][D2z];
  __shared__ float Ps[TTa][Tz];
  __shared__ float Gs[Tz];
  __shared__ float inv_d[TTa];
  __shared__ float mxs[TTa];

  const float* qb = qq + ((size_t)b*Tz + t0)*D2z;
  for (int idx=tid; idx<TTa*D2z/4; idx+=256)
    ((float4*)&Qs[0][0])[idx] = ((const float4*)qb)[idx];
  Gs[tid] = G[b*Tz + tid];
  if (tid < TTa) mxs[tid] = Mx[b*Tz + t0 + tid];
  __syncthreads();

  int s = tid;
  int smax = t0 + TTa - 1;
  {
    float acc[TTa] = {0,0,0,0};
    if (s <= smax){
      const float4* kp = (const float4*)(kk + ((size_t)b*Tz + s)*D2z);
      for (int k4=0; k4<D2z/4; k4++){
        float4 kv = kp[k4];
        #pragma unroll
        for (int tt=0; tt<TTa; tt++){
          float4 qv = ((const float4*)Qs[tt])[k4];
          acc[tt] += dot4(kv,qv);
        }
      }
    }
    float g = Gs[s];
    #pragma unroll
    for (int tt=0; tt<TTa; tt++){
      int t = t0 + tt;
      Ps[tt][s] = (s <= t) ? acc[tt] * __expf(g - mxs[tt]) : 0.f;
    }
  }
  __syncthreads();
  {
    int wv = tid >> 6, lane = tid & 63;
    int tt = wv;
    float ssum = Ps[tt][lane] + Ps[tt][lane+64] + Ps[tt][lane+128] + Ps[tt][lane+192];
    #pragma unroll
    for (int off=1; off<64; off<<=1) ssum += __shfl_xor(ssum, off);
    if (lane==0) inv_d[tt] = 1.f / (fmaxf(fabsf(ssum), 1.f) + 1e-8f);
  }
  __syncthreads();
  {
    int c0 = tid, c1 = tid + 256;
    float a0[TTa]={0,0,0,0}, a1[TTa]={0,0,0,0};
    const float* vb = vv + (size_t)b*Tz*D2z;
    for (int s2=0; s2<=smax; s2+=4){
      float4 pr[TTa];
      #pragma unroll
      for (int tt=0; tt<TTa; tt++) pr[tt] = *(const float4*)&Ps[tt][s2];
      #pragma unroll
      for (int j=0; j<4; j++){
        int sj = s2 + j;
        float v0 = vb[(size_t)sj*D2z + c0];
        float v1 = vb[(size_t)sj*D2z + c1];
        #pragma unroll
        for (int tt=0; tt<TTa; tt++){
          float p = ((const float*)&pr[tt])[j];
          a0[tt] += p*v0; a1[tt] += p*v1;
        }
      }
    }
    float s0=0.f,q0=0.f,s1=0.f,q1=0.f;    // GN partials (c0-group, c1-group)
    #pragma unroll
    for (int tt=0; tt<TTa; tt++){
      size_t row = (size_t)b*Tz + t0 + tt;
      float id = inv_d[tt];
      float h0 = og[row*D2z + c0] * a0[tt] * id;
      float h1 = og[row*D2z + c1] * a1[tt] * id;
      hs[row*D2z + c0] = h0;
      hs[row*D2z + c1] = h1;
      s0+=h0; q0+=h0*h0; s1+=h1; q1+=h1*h1;
    }
    #pragma unroll
    for (int off=1; off<64; off<<=1){
      s0+=__shfl_xor(s0,off); q0+=__shfl_xor(q0,off);
      s1+=__shfl_xor(s1,off); q1+=__shfl_xor(q1,off);
    }
    if ((tid&63)==0){
      int wv=tid>>6, tile=blockIdx.x, half=wv&1;
      int g0=b*4+(wv>>1), g1=b*4+2+(wv>>1);
      float* p0 = gnp + ((size_t)(g0*64+tile)*2+half)*2;
      p0[0]=s0; p0[1]=q0;
      float* p1 = gnp + ((size_t)(g1*64+tile)*2+half)*2;
      p1[0]=s1; p1[1]=q1;
    }
  }
}

// ---------------- finish: GN stats from partials + apply + skip + swish-gate + W_last + residual ----------------
__global__ void __launch_bounds__(512,2) k_final(const float* __restrict__ hs,
    const float* __restrict__ gnp,
    const float* __restrict__ gng, const float* __restrict__ gnb,
    const float* __restrict__ sk, const float* __restrict__ xr,
    const float* __restrict__ WLt, const float* __restrict__ bl,
    const float* __restrict__ x, float* __restrict__ out){
  __shared__ __align__(16) float smem[8192];   // 32KB union
  __shared__ float ls[16];
  __shared__ float gst[8];                     // mu[4], rs[4]
  int r0=blockIdx.x*4; int b=r0>>8; int tid=threadIdx.x;  // 512
  {
    int w=tid>>6, lane=tid&63;
    int g=b*4+(w>>1), half=w&1;
    const float* p = gnp + ((size_t)(g*64+lane)*2 + half)*2;
    float s=p[0], q=p[1];
    #pragma unroll
    for(int off=1;off<64;off<<=1){ s+=__shfl_xor(s,off); q+=__shfl_xor(q,off); }
    if(lane==0){ ls[w*2]=s; ls[w*2+1]=q; }
  }
  __syncthreads();
  if(tid<4){
    float S = ls[4*tid]   + ls[4*tid+2];
    float S2= ls[4*tid+1] + ls[4*tid+3];
    float mu=S*(1.f/(Tz*DHz));
    float var=S2*(1.f/(Tz*DHz))-mu*mu;
    gst[tid]=mu; gst[4+tid]=rsqrtf(fmaxf(var,0.f)+1e-5f);
  }
  __syncthreads();
  float (*hm)[D2z] = (float(*)[D2z])smem;
  for(int idx=tid;idx<4*D2z;idx+=512){
    int tt=idx>>9,c=idx&511;
    size_t row=r0+tt;
    int gl=c>>7;
    float v=hs[row*D2z+c];
    float hg=(v-gst[gl])*gst[4+gl]*gng[c]+gnb[c]+sk[row*D2z+c];
    float xv=xr[row*D2z+c];
    hm[tt][c]=hg*(xv*sigmoidf_(xv));
  }
  __syncthreads();
  int ol=tid&63, ch=tid>>6;   // ch 0..7, k in [ch*64, ch*64+64)
  float4 a0={0,0,0,0},a1={0,0,0,0},a2={0,0,0,0},a3={0,0,0,0};
  const float4* wp=(const float4*)WLt + (size_t)(ch*64)*64 + ol;
  #pragma unroll 2
  for(int kq=0;kq<16;kq++){
    int k=ch*64+kq*4;
    float4 w0=wp[(kq*4+0)*64], w1=wp[(kq*4+1)*64], w2=wp[(kq*4+2)*64], w3=wp[(kq*4+3)*64];
    float4 x0=*(const float4*)&hm[0][k];
    float4 x1=*(const float4*)&hm[1][k];
    float4 x2=*(const float4*)&hm[2][k];
    float4 x3=*(const float4*)&hm[3][k];
    a0=fma4(fma4(fma4(fma4(a0,w0,x0.x),w1,x0.y),w2,x0.z),w3,x0.w);
    a1=fma4(fma4(fma4(fma4(a1,w0,x1.x),w1,x1.y),w2,x1.z),w3,x1.w);
    a2=fma4(fma4(fma4(fma4(a2,w0,x2.x),w1,x2.y),w2,x2.z),w3,x2.w);
    a3=fma4(fma4(fma4(fma4(a3,w0,x3.x),w1,x3.y),w2,x3.z),w3,x3.w);
  }
  __syncthreads();                 // hm dead -> alias red
  float4 (*red)[4][64] = (float4(*)[4][64])smem;   // [8][4][64] float4 = 32KB
  red[ch][0][ol]=a0; red[ch][1][ol]=a1; red[ch][2][ol]=a2; red[ch][3][ol]=a3;
  __syncthreads();
  if(tid<256){
    int tt=tid>>6, oo=tid&63;
    float4 sv={0,0,0,0};
    #pragma unroll
    for(int c2=0;c2<8;c2++) sv=add4(sv,red[c2][tt][oo]);
    float4 bb=((const float4*)bl)[oo];
    float4 xv=((const float4*)(x+(size_t)(r0+tt)*Dz))[oo];
    sv.x+=bb.x+xv.x; sv.y+=bb.y+xv.y; sv.z+=bb.z+xv.z; sv.w+=bb.w+xv.w;
    ((float4*)(out+(size_t)(r0+tt)*Dz))[oo]=sv;
  }
}

extern "C" void kernel_launch(void* const* d_in, const int* in_sizes, int n_in,
                              void* d_out, int out_size, void* d_ws, size_t ws_size,
                              hipStream_t stream) {
  (void)in_sizes; (void)n_in; (void)out_size; (void)ws_size;
  const float* x      = (const float*)d_in[0];
  const float* ln_g   = (const float*)d_in[1];
  const float* ln_b   = (const float*)d_in[2];
  const float* W_left = (const float*)d_in[3];
  const float* b_left = (const float*)d_in[4];
  const float* W_right= (const float*)d_in[5];
  const float* b_right= (const float*)d_in[6];
  const float* Wi     = (const float*)d_in[7];
  const float* bi     = (const float*)d_in[8];
  const float* Wf     = (const float*)d_in[9];
  const float* bf     = (const float*)d_in[10];
  const float* Wo     = (const float*)d_in[11];
  const float* bo     = (const float*)d_in[12];
  const float* Wq     = (const float*)d_in[13];
  const float* Wk     = (const float*)d_in[14];
  const float* Wv     = (const float*)d_in[15];
  const float* conv_w = (const float*)d_in[16];
  const float* conv_b = (const float*)d_in[17];
  const float* skip_W = (const float*)d_in[18];
  const float* gn_g   = (const float*)d_in[19];
  const float* gn_b   = (const float*)d_in[20];
  const float* W_last = (const float*)d_in[21];
  const float* b_last = (const float*)d_in[22];
  float* out = (float*)d_out;

  float* ws = (float*)d_ws;
  float* Wot  = ws;                  // 262144
  float* xl   = ws + 262144;         // 524288
  float* xr   = ws + 786432;         // 524288
  float* xt   = ws + 1310720;        // 524288
  float* og   = ws + 1835008;        // 524288
  float* vv   = ws + 2359296;        // 524288
  float* qq   = ws + 2883584;        // 524288
  float* kk   = ws + 3407872;        // 524288
  float* sk   = ws + 3932160;        // 524288
  float* hs   = ws + 4456448;        // 524288
  float* ibp  = ws + 4980736;        // 2048
  float* fbp  = ws + 4982784;        // 2048
  float* Gd   = ws + 4984864;        // 1024
  float* Mxd  = ws + 4985888;        // 1024
  float* SWt  = ws + 4986912;        // 262144
  float* WLt  = ws + 5249056;        // 131072
  float* Wqt  = ws + 5380128;        // 65536
  float* Wkt  = ws + 5445664;        // 65536
  float* Wvt  = ws + 5511200;        // 65536
  float* CWt  = ws + 5576736;        // 1048576
  float* gnp  = ws + 6625312;        // 4096

  k_pre   <<<720, 512, 0, stream>>>(Wo, skip_W, W_last, Wq, Wk, Wv, conv_w,
                                    Wot, SWt, WLt, Wqt, Wkt, Wvt, CWt,
                                    x, ln_g, ln_b, W_left, b_left, W_right, b_right,
                                    Wi, bi, Wf, bf, xl, xr, ibp, fbp);
  k_mid   <<<1540, 256, 0, stream>>>(xl, CWt, conv_b, xt, Wot, bo, Wvt, og, vv,
                                     ibp, fbp, Gd, Mxd);
  k_qks   <<<dim3(BT/4, 2), 256, 0, stream>>>(xt, SWt, Wqt, Wkt, qq, kk, sk);
  k_attn  <<<dim3(Tz/TTa, Bz), 256, 0, stream>>>(qq, kk, vv, og, Gd, Mxd, hs, gnp);
  k_final <<<BT/4, 512, 0, stream>>>(hs, gnp, gn_g, gn_b, sk, xr, WLt, b_last, x, out);
}

// Round 14
// 156.134 us; speedup vs baseline: 1.1491x; 1.0183x over previous
//
#include <hip/hip_runtime.h>
#include <hip/hip_bf16.h>
#include <cstdint>

// Sizes
#define Bz 4
#define Tz 256
#define Dz 256
#define D2z 512
#define Hz 4
#define DHz 128
#define BT (Bz*Tz)          // 1024 rows

__device__ __forceinline__ float dot4(float4 a, float4 b){
  return a.x*b.x + a.y*b.y + a.z*b.z + a.w*b.w;
}
__device__ __forceinline__ float sigmoidf_(float z){ return 1.f/(1.f+__expf(-z)); }
__device__ __forceinline__ float4 fma4(float4 a, float4 w, float s){
  a.x += w.x*s; a.y += w.y*s; a.z += w.z*s; a.w += w.w*s; return a;
}
__device__ __forceinline__ float4 add4(float4 a, float4 b){
  a.x+=b.x; a.y+=b.y; a.z+=b.z; a.w+=b.w; return a;
}

// ---------------- fused pre: weight transposes (independent) + LN/left/right GEMM ----------------
__global__ void __launch_bounds__(512,2) k_pre(
    const float* __restrict__ Wo, const float* __restrict__ SW,
    const float* __restrict__ Wl, const float* __restrict__ Wq,
    const float* __restrict__ Wk, const float* __restrict__ Wv,
    const float* __restrict__ CW,
    float* __restrict__ Wot, float* __restrict__ SWt, float* __restrict__ WLt,
    float* __restrict__ Wqt, float* __restrict__ Wkt, float* __restrict__ Wvt,
    float* __restrict__ CWt,
    const float* __restrict__ x, const float* __restrict__ lg,
    const float* __restrict__ lb, const float* __restrict__ WL,
    const float* __restrict__ bL, const float* __restrict__ WR,
    const float* __restrict__ bR,
    const float* __restrict__ Wi, const float* __restrict__ bi,
    const float* __restrict__ Wf, const float* __restrict__ bf,
    float* __restrict__ xl, float* __restrict__ xr,
    float* __restrict__ ibp, float* __restrict__ fbp){
  __shared__ __align__(16) float smem[4224];   // 16,896 B
  int bid = blockIdx.x, tid = threadIdx.x;     // 512 thr
  if (bid < 208){
    float (*ts)[65] = (float(*)[65])smem;      // [64][65]
    const float* src; float* dst; int O,K,to,tk;
    if (bid<64){ src=Wo; dst=Wot; O=512;K=512; to=bid>>3; tk=bid&7; }
    else if (bid<128){ int r=bid-64; src=SW; dst=SWt; O=512;K=512; to=r>>3; tk=r&7; }
    else if (bid<160){ int r=bid-128; src=Wl; dst=WLt; O=256;K=512; to=r>>3; tk=r&7; }
    else {
      int r=bid-160; int m=r>>4; int rr=r&15; int h=rr>>2; int s=rr&3;
      src=(m==0?Wq:m==1?Wk:Wv) + h*16384;
      dst=(m==0?Wqt:m==1?Wkt:Wvt) + h*16384;
      O=128; K=128; to=s>>1; tk=s&1;
    }
    int lk=tid&63, ro=tid>>6;    // ro 0..7
    #pragma unroll
    for(int p=0;p<8;p++) ts[p*8+ro][lk] = src[(size_t)(to*64+p*8+ro)*K + tk*64+lk];
    __syncthreads();
    #pragma unroll
    for(int p=0;p<8;p++) dst[(size_t)(tk*64+p*8+ro)*O + to*64+lk] = ts[lk][p*8+ro];
  } else if (bid < 464){
    float4 (*t4)[33] = (float4(*)[33])smem;    // [32][33] float4
    int r = bid-208; int to=r>>4, tk=r&15;
    const float4* src4=(const float4*)CW; float4* dst4=(float4*)CWt;
    int li=tid&31, ro=tid>>5;    // ro 0..15
    #pragma unroll
    for(int p=0;p<2;p++) t4[p*16+ro][li] = src4[(size_t)(to*32+p*16+ro)*512 + tk*32+li];
    __syncthreads();
    #pragma unroll
    for(int p=0;p<2;p++) dst4[(size_t)(tk*32+p*16+ro)*512 + to*32+li] = t4[li][p*16+ro];
  } else {
    float (*xs)[Dz] = (float(*)[Dz])smem;      // [8][256] = 8KB
    float (*rif)[4][8] = (float(*)[4][8])(smem + 8*Dz);  // 64 floats
    int wbid = bid-464;
    int r0 = (wbid&127)*8; int oh = wbid>>7;
    ((float4*)&xs[0][0])[tid] = ((const float4*)(x + (size_t)r0*Dz))[tid];
    __syncthreads();
    int w = tid>>6, lane = tid&63;
    float a0 = xs[w][lane],     a1 = xs[w][lane+64];
    float a2 = xs[w][lane+128], a3 = xs[w][lane+192];
    float s  = a0+a1+a2+a3;
    float s2 = a0*a0+a1*a1+a2*a2+a3*a3;
    #pragma unroll
    for (int off=1; off<64; off<<=1){ s += __shfl_xor(s, off); s2 += __shfl_xor(s2, off); }
    float mu = s*(1.f/Dz);
    float rs = rsqrtf(s2*(1.f/Dz)-mu*mu+1e-5f);
    xs[w][lane]     = (a0-mu)*rs*lg[lane]    +lb[lane];
    xs[w][lane+64]  = (a1-mu)*rs*lg[lane+64] +lb[lane+64];
    xs[w][lane+128] = (a2-mu)*rs*lg[lane+128]+lb[lane+128];
    xs[w][lane+192] = (a3-mu)*rs*lg[lane+192]+lb[lane+192];
    __syncthreads();
    int which = tid>>8;               // 0 -> WL (+i/f), 1 -> WR
    int o = oh*256 + (tid&255);
    float acc[8]={0,0,0,0,0,0,0,0};
    const float* WM = which ? WR : WL;
    const float4* wm4 = (const float4*)(WM + (size_t)o*Dz);
    #pragma unroll 2
    for (int k4=0;k4<Dz/4;k4++){
      float4 wv=wm4[k4];
      #pragma unroll
      for(int tt=0;tt<8;tt++) acc[tt] += dot4(wv, ((const float4*)xs[tt])[k4]);
    }
    if (which==0){
      float blv=bL[o], wi_o=Wi[o], wf_o=Wf[o];
      float pi[8], pf[8];
      #pragma unroll
      for(int tt=0;tt<8;tt++){
        float xlv = acc[tt]+blv;
        xl[(size_t)(r0+tt)*D2z+o]=xlv;
        pi[tt]=xlv*wi_o; pf[tt]=xlv*wf_o;
      }
      #pragma unroll
      for(int off=1;off<64;off<<=1){
        #pragma unroll
        for(int tt=0;tt<8;tt++){ pi[tt]+=__shfl_xor(pi[tt],off); pf[tt]+=__shfl_xor(pf[tt],off); }
      }
      if(lane==0){
        #pragma unroll
        for(int tt=0;tt<8;tt++){ rif[0][w][tt]=pi[tt]; rif[1][w][tt]=pf[tt]; }
      }
    } else {
      float brv=bR[o];
      #pragma unroll
      for(int tt=0;tt<8;tt++) xr[(size_t)(r0+tt)*D2z+o]=acc[tt]+brv;
    }
    __syncthreads();
    if(tid<16){
      int r=tid&7, which2=tid>>3;
      float sv=0.f;
      #pragma unroll
      for(int ww=0;ww<4;ww++) sv+=rif[which2][ww][r];
      float bias = (oh==0) ? (which2==0 ? bi[0] : bf[0]) : 0.f;
      (which2==0 ? ibp : fbp)[oh*BT + r0 + r] = sv + bias;
    }
  }
}

// ---------------- fused mid: conv (2 outs/thread: LDS-pipe rebalance) + wov + decay ----------------
// Conv inner step: 19 ds_read_b128 now feed 512 FMA (2 outs x 16 t) -> LDS:VALU ~0.9
// (was 1.8, LDS-pipe-bound at VALUBusy 65%). Weight L2 traffic unchanged (64 t-tiles).
__global__ void __launch_bounds__(256,2) k_mid(
    const float* __restrict__ xl, const float* __restrict__ CWt,
    const float* __restrict__ cb, float* __restrict__ xt,
    const float* __restrict__ Wot, const float* __restrict__ bo,
    const float* __restrict__ Wvt, float* __restrict__ og, float* __restrict__ vv,
    const float* __restrict__ ibp, const float* __restrict__ fbp,
    float* __restrict__ G, float* __restrict__ Mx){
  __shared__ __align__(16) float smem[9728];    // 38,912 B
  int bid = blockIdx.x, tid = threadIdx.x;      // 256 thr
  if (bid < 512){
    // ---------------- conv: t-tile 16, 64-out group, thread = 2 outs x 8 ic-chunks of 64 ----------------
    float (*xs)[D2z] = (float(*)[D2z])smem;     // [19][512] = 38,912 B
    int tile = bid&63, o0 = (bid>>6)*64;        // 8 o-groups of 64
    int b = tile>>4; int t0 = (tile&15)*16;
    for(int idx=tid; idx<19*(D2z/4); idx+=256){
      int j = idx>>7, k4 = idx&127;
      int t = t0-3+j;
      float4 v = (t>=0) ? ((const float4*)(xl + (size_t)((b<<8)+t)*D2z))[k4]
                        : make_float4(0.f,0.f,0.f,0.f);
      ((float4*)xs[j])[k4]=v;
    }
    __syncthreads();
    int ol = tid&31, ch = tid>>5;               // 32 out-slots x 8 chunks of 64 ic
    int oA = o0+ol, oB = o0+ol+32, ic0 = ch*64;
    float accA[16], accB[16];
    #pragma unroll
    for(int tt=0;tt<16;tt++){ accA[tt]=0.f; accB[tt]=0.f; }
    const float4* wA = (const float4*)CWt + oA;  // quad index [i*512 + o]
    const float4* wB = (const float4*)CWt + oB;
    for(int i=0;i<64;i+=4){
      int ig = ic0+i;
      float4 a0=wA[(size_t)(ig+0)*512], a1=wA[(size_t)(ig+1)*512];
      float4 a2=wA[(size_t)(ig+2)*512], a3=wA[(size_t)(ig+3)*512];
      float4 b0=wB[(size_t)(ig+0)*512], b1=wB[(size_t)(ig+1)*512];
      float4 b2=wB[(size_t)(ig+2)*512], b3=wB[(size_t)(ig+3)*512];
      float4 xr4[19];
      #pragma unroll
      for(int j=0;j<19;j++) xr4[j]=*(const float4*)&xs[j][ig];
      #pragma unroll
      for(int tt=0;tt<16;tt++){
        accA[tt] += a0.x*xr4[tt].x + a0.y*xr4[tt+1].x + a0.z*xr4[tt+2].x + a0.w*xr4[tt+3].x
                  + a1.x*xr4[tt].y + a1.y*xr4[tt+1].y + a1.z*xr4[tt+2].y + a1.w*xr4[tt+3].y
                  + a2.x*xr4[tt].z + a2.y*xr4[tt+1].z + a2.z*xr4[tt+2].z + a2.w*xr4[tt+3].z
                  + a3.x*xr4[tt].w + a3.y*xr4[tt+1].w + a3.z*xr4[tt+2].w + a3.w*xr4[tt+3].w;
        accB[tt] += b0.x*xr4[tt].x + b0.y*xr4[tt+1].x + b0.z*xr4[tt+2].x + b0.w*xr4[tt+3].x
                  + b1.x*xr4[tt].y + b1.y*xr4[tt+1].y + b1.z*xr4[tt+2].y + b1.w*xr4[tt+3].y
                  + b2.x*xr4[tt].z + b2.y*xr4[tt+1].z + b2.z*xr4[tt+2].z + b2.w*xr4[tt+3].z
                  + b3.x*xr4[tt].w + b3.y*xr4[tt+1].w + b3.z*xr4[tt+2].w + b3.w*xr4[tt+3].w;
      }
    }
    __syncthreads();                            // xs dead; alias red onto it
    float (*red)[64][17] = (float(*)[64][17])smem;   // [8][64][17] = 34,816 B
    #pragma unroll
    for(int tt=0;tt<16;tt++){ red[ch][ol][tt]=accA[tt]; red[ch][ol+32][tt]=accB[tt]; }
    __syncthreads();
    for(int idx=tid; idx<1024; idx+=256){
      int oo = idx&63, t = idx>>6;
      float y = red[0][oo][t]+red[1][oo][t]+red[2][oo][t]+red[3][oo][t]
              + red[4][oo][t]+red[5][oo][t]+red[6][oo][t]+red[7][oo][t] + cb[o0+oo];
      xt[(size_t)((b<<8)+t0+t)*D2z + o0+oo] = y*sigmoidf_(y);
    }
  } else if (bid < 1024){
    // ---------------- wov (two-pass over one reduce buffer) ----------------
    float (*xs)[D2z] = (float(*)[D2z])smem;                    // [4][512] 8KB
    float4 (*red)[4][64] = (float4(*)[4][64])(smem + 2048);    // 16KB
    int wbid = bid-512;
    int r0=(wbid&255)*4; int oh=wbid>>8;
    for(int idx=tid;idx<512;idx+=256)
      ((float4*)&xs[0][0])[idx]=((const float4*)(xl+(size_t)r0*D2z))[idx];
    __syncthreads();
    int ol=tid&63, ch=tid>>6;
    // pass O: o-gate GEMM
    {
      float4 a0={0,0,0,0},a1={0,0,0,0},a2={0,0,0,0},a3={0,0,0,0};
      const float4* wp=(const float4*)Wot + (size_t)ch*16384 + (oh*64+ol);
      #pragma unroll 2
      for(int kq=0;kq<32;kq++){
        int k=ch*128+kq*4;
        float4 w0=wp[(kq*4+0)*128], w1=wp[(kq*4+1)*128], w2=wp[(kq*4+2)*128], w3=wp[(kq*4+3)*128];
        float4 x0=*(const float4*)&xs[0][k];
        float4 x1=*(const float4*)&xs[1][k];
        float4 x2=*(const float4*)&xs[2][k];
        float4 x3=*(const float4*)&xs[3][k];
        a0=fma4(fma4(fma4(fma4(a0,w0,x0.x),w1,x0.y),w2,x0.z),w3,x0.w);
        a1=fma4(fma4(fma4(fma4(a1,w0,x1.x),w1,x1.y),w2,x1.z),w3,x1.w);
        a2=fma4(fma4(fma4(fma4(a2,w0,x2.x),w1,x2.y),w2,x2.z),w3,x2.w);
        a3=fma4(fma4(fma4(fma4(a3,w0,x3.x),w1,x3.y),w2,x3.z),w3,x3.w);
      }
      red[ch][0][ol]=a0; red[ch][1][ol]=a1; red[ch][2][ol]=a2; red[ch][3][ol]=a3;
    }
    __syncthreads();
    {
      float4 s=add4(add4(red[0][ch][ol],red[1][ch][ol]),add4(red[2][ch][ol],red[3][ch][ol]));
      float4 bb=((const float4*)bo)[oh*64+ol];
      s.x=sigmoidf_(s.x+bb.x); s.y=sigmoidf_(s.y+bb.y);
      s.z=sigmoidf_(s.z+bb.z); s.w=sigmoidf_(s.w+bb.w);
      ((float4*)(og+(size_t)(r0+ch)*D2z))[oh*64+ol]=s;
    }
    __syncthreads();
    // pass V: block-diag v
    {
      int h = oh*2 + (ol>>5), odq = ol&31;
      float4 v0={0,0,0,0},v1={0,0,0,0},v2={0,0,0,0},v3={0,0,0,0};
      const float4* wv=(const float4*)Wvt + (size_t)h*4096 + (size_t)(ch*32)*32 + odq;
      int xoff = h*128 + ch*32;
      #pragma unroll 2
      for(int iq=0;iq<8;iq++){
        float4 w0=wv[(iq*4+0)*32], w1=wv[(iq*4+1)*32], w2=wv[(iq*4+2)*32], w3=wv[(iq*4+3)*32];
        float4 x0=*(const float4*)&xs[0][xoff+iq*4];
        float4 x1=*(const float4*)&xs[1][xoff+iq*4];
        float4 x2=*(const float4*)&xs[2][xoff+iq*4];
        float4 x3=*(const float4*)&xs[3][xoff+iq*4];
        v0=fma4(fma4(fma4(fma4(v0,w0,x0.x),w1,x0.y),w2,x0.z),w3,x0.w);
        v1=fma4(fma4(fma4(fma4(v1,w0,x1.x),w1,x1.y),w2,x1.z),w3,x1.w);
        v2=fma4(fma4(fma4(fma4(v2,w0,x2.x),w1,x2.y),w2,x2.z),w3,x2.w);
        v3=fma4(fma4(fma4(fma4(v3,w0,x3.x),w1,x3.y),w2,x3.z),w3,x3.w);
      }
      red[ch][0][ol]=v0; red[ch][1][ol]=v1; red[ch][2][ol]=v2; red[ch][3][ol]=v3;
    }
    __syncthreads();
    {
      float4 vs=add4(add4(red[0][ch][ol],red[1][ch][ol]),add4(red[2][ch][ol],red[3][ch][ol]));
      ((float4*)(vv+(size_t)(r0+ch)*D2z))[oh*64+ol]=vs;
    }
  } else {
    // ---------------- decay ----------------
    float* buf = smem;
    int b = bid-1024, t = tid;
    float f = fbp[b*Tz + t] + fbp[BT + b*Tz + t];
    float ibv = ibp[b*Tz + t] + ibp[BT + b*Tz + t];
    buf[t] = f; __syncthreads();
    float v = f;
    for (int off=1; off<Tz; off<<=1){
      float add = (t >= off) ? buf[t-off] : 0.f;
      __syncthreads();
      v += add; buf[t] = v;
      __syncthreads();
    }
    float F = v;
    float g = ibv - F;
    G[b*Tz+t] = g;
    buf[t] = g; __syncthreads();
    v = g;
    for (int off=1; off<Tz; off<<=1){
      float other = (t >= off) ? buf[t-off] : -3.4e38f;
      __syncthreads();
      v = fmaxf(v, other); buf[t] = v;
      __syncthreads();
    }
    Mx[b*Tz+t] = fmaxf(v, 0.f);
  }
}

// ---------------- q,k (block-diag) + skip GEMM: three passes over one reduce buffer ----------------
__global__ void __launch_bounds__(256,2) k_qks(const float* __restrict__ xt,
    const float* __restrict__ SWt, const float* __restrict__ Wqt,
    const float* __restrict__ Wkt,
    float* __restrict__ qq, float* __restrict__ kk, float* __restrict__ sk){
  __shared__ __align__(16) float smem[6144];                // 24,576 B
  float (*xs)[D2z] = (float(*)[D2z])smem;                   // 8KB
  float4 (*red)[4][64] = (float4(*)[4][64])(smem + 2048);   // 16KB
  int r0=blockIdx.x*4; int oh=blockIdx.y; int tid=threadIdx.x;
  for(int idx=tid;idx<512;idx+=256)
    ((float4*)&xs[0][0])[idx]=((const float4*)(xt+(size_t)r0*D2z))[idx];
  __syncthreads();
  int ol=tid&63, ch=tid>>6;
  // ---- pass S: skip GEMM ----
  {
    float4 s0={0,0,0,0},s1={0,0,0,0},s2={0,0,0,0},s3={0,0,0,0};
    const float4* wp=(const float4*)SWt + (size_t)ch*16384 + (oh*64+ol);
    #pragma unroll 2
    for(int kq=0;kq<32;kq++){
      int k=ch*128+kq*4;
      float4 w0=wp[(kq*4+0)*128], w1=wp[(kq*4+1)*128], w2=wp[(kq*4+2)*128], w3=wp[(kq*4+3)*128];
      float4 x0=*(const float4*)&xs[0][k];
      float4 x1=*(const float4*)&xs[1][k];
      float4 x2=*(const float4*)&xs[2][k];
      float4 x3=*(const float4*)&xs[3][k];
      s0=fma4(fma4(fma4(fma4(s0,w0,x0.x),w1,x0.y),w2,x0.z),w3,x0.w);
      s1=fma4(fma4(fma4(fma4(s1,w0,x1.x),w1,x1.y),w2,x1.z),w3,x1.w);
      s2=fma4(fma4(fma4(fma4(s2,w0,x2.x),w1,x2.y),w2,x2.z),w3,x2.w);
      s3=fma4(fma4(fma4(fma4(s3,w0,x3.x),w1,x3.y),w2,x3.z),w3,x3.w);
    }
    red[ch][0][ol]=s0; red[ch][1][ol]=s1; red[ch][2][ol]=s2; red[ch][3][ol]=s3;
  }
  __syncthreads();
  {
    float4 sv=add4(add4(red[0][ch][ol],red[1][ch][ol]),add4(red[2][ch][ol],red[3][ch][ol]));
    ((float4*)(sk+(size_t)(r0+ch)*D2z))[oh*64+ol]=sv;
  }
  __syncthreads();
  int h = oh*2 + (ol>>5), odq = ol&31;
  int xoff = h*128 + ch*32;
  // ---- pass Q ----
  {
    float4 q0={0,0,0,0},q1={0,0,0,0},q2={0,0,0,0},q3={0,0,0,0};
    const float4* wq=(const float4*)Wqt + (size_t)h*4096 + (size_t)(ch*32)*32 + odq;
    #pragma unroll 2
    for(int iq=0;iq<8;iq++){
      float4 w0=wq[(iq*4+0)*32], w1=wq[(iq*4+1)*32], w2=wq[(iq*4+2)*32], w3=wq[(iq*4+3)*32];
      float4 x0=*(const float4*)&xs[0][xoff+iq*4];
      float4 x1=*(const float4*)&xs[1][xoff+iq*4];
      float4 x2=*(const float4*)&xs[2][xoff+iq*4];
      float4 x3=*(const float4*)&xs[3][xoff+iq*4];
      q0=fma4(fma4(fma4(fma4(q0,w0,x0.x),w1,x0.y),w2,x0.z),w3,x0.w);
      q1=fma4(fma4(fma4(fma4(q1,w0,x1.x),w1,x1.y),w2,x1.z),w3,x1.w);
      q2=fma4(fma4(fma4(fma4(q2,w0,x2.x),w1,x2.y),w2,x2.z),w3,x2.w);
      q3=fma4(fma4(fma4(fma4(q3,w0,x3.x),w1,x3.y),w2,x3.z),w3,x3.w);
    }
    red[ch][0][ol]=q0; red[ch][1][ol]=q1; red[ch][2][ol]=q2; red[ch][3][ol]=q3;
  }
  __syncthreads();
  {
    float4 qv=add4(add4(red[0][ch][ol],red[1][ch][ol]),add4(red[2][ch][ol],red[3][ch][ol]));
    ((float4*)(qq+(size_t)(r0+ch)*D2z))[oh*64+ol]=qv;
  }
  __syncthreads();
  // ---- pass K ----
  {
    float4 k0={0,0,0,0},k1={0,0,0,0},k2={0,0,0,0},k3={0,0,0,0};
    const float4* wk=(const float4*)Wkt + (size_t)h*4096 + (size_t)(ch*32)*32 + odq;
    #pragma unroll 2
    for(int iq=0;iq<8;iq++){
      float4 w0=wk[(iq*4+0)*32], w1=wk[(iq*4+1)*32], w2=wk[(iq*4+2)*32], w3=wk[(iq*4+3)*32];
      float4 x0=*(const float4*)&xs[0][xoff+iq*4];
      float4 x1=*(const float4*)&xs[1][xoff+iq*4];
      float4 x2=*(const float4*)&xs[2][xoff+iq*4];
      float4 x3=*(const float4*)&xs[3][xoff+iq*4];
      k0=fma4(fma4(fma4(fma4(k0,w0,x0.x),w1,x0.y),w2,x0.z),w3,x0.w);
      k1=fma4(fma4(fma4(fma4(k1,w0,x1.x),w1,x1.y),w2,x1.z),w3,x1.w);
      k2=fma4(fma4(fma4(fma4(k2,w0,x2.x),w1,x2.y),w2,x2.z),w3,x2.w);
      k3=fma4(fma4(fma4(fma4(k3,w0,x3.x),w1,x3.y),w2,x3.z),w3,x3.w);
    }
    red[ch][0][ol]=k0; red[ch][1][ol]=k1; red[ch][2][ol]=k2; red[ch][3][ol]=k3;
  }
  __syncthreads();
  {
    float4 kv=add4(add4(red[0][ch][ol],red[1][ch][ol]),add4(red[2][ch][ol],red[3][ch][ol]));
    kv.x*=0.0625f; kv.y*=0.0625f; kv.z*=0.0625f; kv.w*=0.0625f;   // SCALE = D^-0.5
    ((float4*)(kk+(size_t)(r0+ch)*D2z))[oh*64+ol]=kv;
  }
}

// ---------------- scan as causal decayed attention + deterministic GN partials ----------------
#define TTa 4
__global__ void __launch_bounds__(256) k_attn(
    const float* __restrict__ qq, const float* __restrict__ kk,
    const float* __restrict__ vv, const float* __restrict__ og,
    const float* __restrict__ G, const float* __restrict__ Mx,
    float* __restrict__ hs, float* __restrict__ gnp){
  int b  = blockIdx.y;
  int t0 = blockIdx.x * TTa;
  int tid = threadIdx.x;            // 256
  __shared__ float Qs[TTa][D2z];
  __shared__ float Ps[TTa][Tz];
  __shared__ float Gs[Tz];
  __shared__ float inv_d[TTa];
  __shared__ float mxs[TTa];

  const float* qb = qq + ((size_t)b*Tz + t0)*D2z;
  for (int idx=tid; idx<TTa*D2z/4; idx+=256)
    ((float4*)&Qs[0][0])[idx] = ((const float4*)qb)[idx];
  Gs[tid] = G[b*Tz + tid];
  if (tid < TTa) mxs[tid] = Mx[b*Tz + t0 + tid];
  __syncthreads();

  int s = tid;
  int smax = t0 + TTa - 1;
  {
    float acc[TTa] = {0,0,0,0};
    if (s <= smax){
      const float4* kp = (const float4*)(kk + ((size_t)b*Tz + s)*D2z);
      for (int k4=0; k4<D2z/4; k4++){
        float4 kv = kp[k4];
        #pragma unroll
        for (int tt=0; tt<TTa; tt++){
          float4 qv = ((const float4*)Qs[tt])[k4];
          acc[tt] += dot4(kv,qv);
        }
      }
    }
    float g = Gs[s];
    #pragma unroll
    for (int tt=0; tt<TTa; tt++){
      int t = t0 + tt;
      Ps[tt][s] = (s <= t) ? acc[tt] * __expf(g - mxs[tt]) : 0.f;
    }
  }
  __syncthreads();
  {
    int wv = tid >> 6, lane = tid & 63;
    int tt = wv;
    float ssum = Ps[tt][lane] + Ps[tt][lane+64] + Ps[tt][lane+128] + Ps[tt][lane+192];
    #pragma unroll
    for (int off=1; off<64; off<<=1) ssum += __shfl_xor(ssum, off);
    if (lane==0) inv_d[tt] = 1.f / (fmaxf(fabsf(ssum), 1.f) + 1e-8f);
  }
  __syncthreads();
  {
    int c0 = tid, c1 = tid + 256;
    float a0[TTa]={0,0,0,0}, a1[TTa]={0,0,0,0};
    const float* vb = vv + (size_t)b*Tz*D2z;
    for (int s2=0; s2<=smax; s2+=4){
      float4 pr[TTa];
      #pragma unroll
      for (int tt=0; tt<TTa; tt++) pr[tt] = *(const float4*)&Ps[tt][s2];
      #pragma unroll
      for (int j=0; j<4; j++){
        int sj = s2 + j;
        float v0 = vb[(size_t)sj*D2z + c0];
        float v1 = vb[(size_t)sj*D2z + c1];
        #pragma unroll
        for (int tt=0; tt<TTa; tt++){
          float p = ((const float*)&pr[tt])[j];
          a0[tt] += p*v0; a1[tt] += p*v1;
        }
      }
    }
    float s0=0.f,q0=0.f,s1=0.f,q1=0.f;    // GN partials (c0-group, c1-group)
    #pragma unroll
    for (int tt=0; tt<TTa; tt++){
      size_t row = (size_t)b*Tz + t0 + tt;
      float id = inv_d[tt];
      float h0 = og[row*D2z + c0] * a0[tt] * id;
      float h1 = og[row*D2z + c1] * a1[tt] * id;
      hs[row*D2z + c0] = h0;
      hs[row*D2z + c1] = h1;
      s0+=h0; q0+=h0*h0; s1+=h1; q1+=h1*h1;
    }
    #pragma unroll
    for (int off=1; off<64; off<<=1){
      s0+=__shfl_xor(s0,off); q0+=__shfl_xor(q0,off);
      s1+=__shfl_xor(s1,off); q1+=__shfl_xor(q1,off);
    }
    if ((tid&63)==0){
      int wv=tid>>6, tile=blockIdx.x, half=wv&1;
      int g0=b*4+(wv>>1), g1=b*4+2+(wv>>1);
      float* p0 = gnp + ((size_t)(g0*64+tile)*2+half)*2;
      p0[0]=s0; p0[1]=q0;
      float* p1 = gnp + ((size_t)(g1*64+tile)*2+half)*2;
      p1[0]=s1; p1[1]=q1;
    }
  }
}

// ---------------- finish: GN stats from partials + apply + skip + swish-gate + W_last + residual ----------------
__global__ void __launch_bounds__(512,2) k_final(const float* __restrict__ hs,
    const float* __restrict__ gnp,
    const float* __restrict__ gng, const float* __restrict__ gnb,
    const float* __restrict__ sk, const float* __restrict__ xr,
    const float* __restrict__ WLt, const float* __restrict__ bl,
    const float* __restrict__ x, float* __restrict__ out){
  __shared__ __align__(16) float smem[8192];   // 32KB union
  __shared__ float ls[16];
  __shared__ float gst[8];                     // mu[4], rs[4]
  int r0=blockIdx.x*4; int b=r0>>8; int tid=threadIdx.x;  // 512
  {
    int w=tid>>6, lane=tid&63;
    int g=b*4+(w>>1), half=w&1;
    const float* p = gnp + ((size_t)(g*64+lane)*2 + half)*2;
    float s=p[0], q=p[1];
    #pragma unroll
    for(int off=1;off<64;off<<=1){ s+=__shfl_xor(s,off); q+=__shfl_xor(q,off); }
    if(lane==0){ ls[w*2]=s; ls[w*2+1]=q; }
  }
  __syncthreads();
  if(tid<4){
    float S = ls[4*tid]   + ls[4*tid+2];
    float S2= ls[4*tid+1] + ls[4*tid+3];
    float mu=S*(1.f/(Tz*DHz));
    float var=S2*(1.f/(Tz*DHz))-mu*mu;
    gst[tid]=mu; gst[4+tid]=rsqrtf(fmaxf(var,0.f)+1e-5f);
  }
  __syncthreads();
  float (*hm)[D2z] = (float(*)[D2z])smem;
  for(int idx=tid;idx<4*D2z;idx+=512){
    int tt=idx>>9,c=idx&511;
    size_t row=r0+tt;
    int gl=c>>7;
    float v=hs[row*D2z+c];
    float hg=(v-gst[gl])*gst[4+gl]*gng[c]+gnb[c]+sk[row*D2z+c];
    float xv=xr[row*D2z+c];
    hm[tt][c]=hg*(xv*sigmoidf_(xv));
  }
  __syncthreads();
  int ol=tid&63, ch=tid>>6;   // ch 0..7, k in [ch*64, ch*64+64)
  float4 a0={0,0,0,0},a1={0,0,0,0},a2={0,0,0,0},a3={0,0,0,0};
  const float4* wp=(const float4*)WLt + (size_t)(ch*64)*64 + ol;
  #pragma unroll 2
  for(int kq=0;kq<16;kq++){
    int k=ch*64+kq*4;
    float4 w0=wp[(kq*4+0)*64], w1=wp[(kq*4+1)*64], w2=wp[(kq*4+2)*64], w3=wp[(kq*4+3)*64];
    float4 x0=*(const float4*)&hm[0][k];
    float4 x1=*(const float4*)&hm[1][k];
    float4 x2=*(const float4*)&hm[2][k];
    float4 x3=*(const float4*)&hm[3][k];
    a0=fma4(fma4(fma4(fma4(a0,w0,x0.x),w1,x0.y),w2,x0.z),w3,x0.w);
    a1=fma4(fma4(fma4(fma4(a1,w0,x1.x),w1,x1.y),w2,x1.z),w3,x1.w);
    a2=fma4(fma4(fma4(fma4(a2,w0,x2.x),w1,x2.y),w2,x2.z),w3,x2.w);
    a3=fma4(fma4(fma4(fma4(a3,w0,x3.x),w1,x3.y),w2,x3.z),w3,x3.w);
  }
  __syncthreads();                 // hm dead -> alias red
  float4 (*red)[4][64] = (float4(*)[4][64])smem;   // [8][4][64] float4 = 32KB
  red[ch][0][ol]=a0; red[ch][1][ol]=a1; red[ch][2][ol]=a2; red[ch][3][ol]=a3;
  __syncthreads();
  if(tid<256){
    int tt=tid>>6, oo=tid&63;
    float4 sv={0,0,0,0};
    #pragma unroll
    for(int c2=0;c2<8;c2++) sv=add4(sv,red[c2][tt][oo]);
    float4 bb=((const float4*)bl)[oo];
    float4 xv=((const float4*)(x+(size_t)(r0+tt)*Dz))[oo];
    sv.x+=bb.x+xv.x; sv.y+=bb.y+xv.y; sv.z+=bb.z+xv.z; sv.w+=bb.w+xv.w;
    ((float4*)(out+(size_t)(r0+tt)*Dz))[oo]=sv;
  }
}

extern "C" void kernel_launch(void* const* d_in, const int* in_sizes, int n_in,
                              void* d_out, int out_size, void* d_ws, size_t ws_size,
                              hipStream_t stream) {
  (void)in_sizes; (void)n_in; (void)out_size; (void)ws_size;
  const float* x      = (const float*)d_in[0];
  const float* ln_g   = (const float*)d_in[1];
  const float* ln_b   = (const float*)d_in[2];
  const float* W_left = (const float*)d_in[3];
  const float* b_left = (const float*)d_in[4];
  const float* W_right= (const float*)d_in[5];
  const float* b_right= (const float*)d_in[6];
  const float* Wi     = (const float*)d_in[7];
  const float* bi     = (const float*)d_in[8];
  const float* Wf     = (const float*)d_in[9];
  const float* bf     = (const float*)d_in[10];
  const float* Wo     = (const float*)d_in[11];
  const float* bo     = (const float*)d_in[12];
  const float* Wq     = (const float*)d_in[13];
  const float* Wk     = (const float*)d_in[14];
  const float* Wv     = (const float*)d_in[15];
  const float* conv_w = (const float*)d_in[16];
  const float* conv_b = (const float*)d_in[17];
  const float* skip_W = (const float*)d_in[18];
  const float* gn_g   = (const float*)d_in[19];
  const float* gn_b   = (const float*)d_in[20];
  const float* W_last = (const float*)d_in[21];
  const float* b_last = (const float*)d_in[22];
  float* out = (float*)d_out;

  float* ws = (float*)d_ws;
  float* Wot  = ws;                  // 262144
  float* xl   = ws + 262144;         // 524288
  float* xr   = ws + 786432;         // 524288
  float* xt   = ws + 1310720;        // 524288
  float* og   = ws + 1835008;        // 524288
  float* vv   = ws + 2359296;        // 524288
  float* qq   = ws + 2883584;        // 524288
  float* kk   = ws + 3407872;        // 524288
  float* sk   = ws + 3932160;        // 524288
  float* hs   = ws + 4456448;        // 524288
  float* ibp  = ws + 4980736;        // 2048
  float* fbp  = ws + 4982784;        // 2048
  float* Gd   = ws + 4984864;        // 1024
  float* Mxd  = ws + 4985888;        // 1024
  float* SWt  = ws + 4986912;        // 262144
  float* WLt  = ws + 5249056;        // 131072
  float* Wqt  = ws + 5380128;        // 65536
  float* Wkt  = ws + 5445664;        // 65536
  float* Wvt  = ws + 5511200;        // 65536
  float* CWt  = ws + 5576736;        // 1048576
  float* gnp  = ws + 6625312;        // 4096

  k_pre   <<<720, 512, 0, stream>>>(Wo, skip_W, W_last, Wq, Wk, Wv, conv_w,
                                    Wot, SWt, WLt, Wqt, Wkt, Wvt, CWt,
                                    x, ln_g, ln_b, W_left, b_left, W_right, b_right,
                                    Wi, bi, Wf, bf, xl, xr, ibp, fbp);
  k_mid   <<<1028, 256, 0, stream>>>(xl, CWt, conv_b, xt, Wot, bo, Wvt, og, vv,
                                     ibp, fbp, Gd, Mxd);
  k_qks   <<<dim3(BT/4, 2), 256, 0, stream>>>(xt, SWt, Wqt, Wkt, qq, kk, sk);
  k_attn  <<<dim3(Tz/TTa, Bz), 256, 0, stream>>>(qq, kk, vv, og, Gd, Mxd, hs, gnp);
  k_final <<<BT/4, 512, 0, stream>>>(hs, gnp, gn_g, gn_b, sk, xr, WLt, b_last, x, out);
}